// Round 12
// baseline (106.939 us; speedup 1.0000x reference)
//
#include <hip/hip_runtime.h>
#include <stdint.h>

typedef unsigned short u16;
typedef unsigned int u32;
typedef __bf16 bf16x8 __attribute__((ext_vector_type(8)));
typedef float f32x4 __attribute__((ext_vector_type(4)));

#define NBATCH 8
#define NPT    2048
#define NPTS   16384     // NBATCH*NPT
#define INDIM  256
#define DD     512
#define GG     64        // 8x8 grid cells

__device__ __forceinline__ u16 f2bf(float f){
  u32 u = __builtin_bit_cast(u32, f);
  u += 0x7fffu + ((u >> 16) & 1u);
  return (u16)(u >> 16);
}
__device__ __forceinline__ float bf2f(u16 h){
  u32 u = ((u32)h) << 16;
  return __builtin_bit_cast(float, u);
}
__device__ __forceinline__ void load8(const float* __restrict__ p, float* r){
  float4 a = *(const float4*)p;
  float4 b = *(const float4*)(p + 4);
  r[0]=a.x;r[1]=a.y;r[2]=a.z;r[3]=a.w;r[4]=b.x;r[5]=b.y;r[6]=b.z;r[7]=b.w;
}
__device__ __forceinline__ void load8bf(const u16* __restrict__ p, float* r){
  uint4 v = *(const uint4*)p;
  r[0]=bf2f((u16)v.x); r[1]=bf2f((u16)(v.x>>16));
  r[2]=bf2f((u16)v.y); r[3]=bf2f((u16)(v.y>>16));
  r[4]=bf2f((u16)v.z); r[5]=bf2f((u16)(v.z>>16));
  r[6]=bf2f((u16)v.w); r[7]=bf2f((u16)(v.w>>16));
}
__device__ __forceinline__ void load8bf_lds(const u16* p, float* r){
  uint4 v = *(const uint4*)p;
  r[0]=bf2f((u16)v.x); r[1]=bf2f((u16)(v.x>>16));
  r[2]=bf2f((u16)v.y); r[3]=bf2f((u16)(v.y>>16));
  r[4]=bf2f((u16)v.z); r[5]=bf2f((u16)(v.z>>16));
  r[6]=bf2f((u16)v.w); r[7]=bf2f((u16)(v.w>>16));
}
__device__ __forceinline__ void store8(float* __restrict__ p, const float* r){
  float4 a; a.x=r[0];a.y=r[1];a.z=r[2];a.w=r[3];
  float4 b; b.x=r[4];b.y=r[5];b.z=r[6];b.w=r[7];
  *(float4*)p = a; *(float4*)(p+4) = b;
}
__device__ __forceinline__ uint4 pack8(const float* a){
  uint4 pk;
  pk.x = (u32)f2bf(a[0]) | ((u32)f2bf(a[1]) << 16);
  pk.y = (u32)f2bf(a[2]) | ((u32)f2bf(a[3]) << 16);
  pk.z = (u32)f2bf(a[4]) | ((u32)f2bf(a[5]) << 16);
  pk.w = (u32)f2bf(a[6]) | ((u32)f2bf(a[7]) << 16);
  return pk;
}
typedef __attribute__((address_space(1))) unsigned as1u;
typedef __attribute__((address_space(3))) unsigned as3u;
__device__ __forceinline__ void gload16(const void* g, void* l){
  __builtin_amdgcn_global_load_lds((as1u*)(uintptr_t)g, (as3u*)(uintptr_t)l, 16, 0, 0);
}

// ---- 64x64 LDS-tiled transpose: src f32[*][scols] -> dst bf16[*][dcols] ----
__device__ __forceinline__ void transpose64(const float* __restrict__ src, int scols,
                                            u16* __restrict__ dst, int dcols,
                                            int r0, int c0, char* smem, int t){
  float (*sh)[65] = (float(*)[65])smem;
  #pragma unroll
  for (int i = 0; i < 16; i++){
    int idx = i*256 + t;
    int r = idx >> 6, c = idx & 63;
    sh[r][c] = src[(size_t)(r0 + r)*scols + c0 + c];
  }
  __syncthreads();
  #pragma unroll
  for (int i = 0; i < 8; i++){
    int idx = i*512 + t*2;
    int oR = idx >> 6, oC = idx & 63;
    u32 pk = (u32)f2bf(sh[oC][oR]) | ((u32)f2bf(sh[oC+1][oR]) << 16);
    *(u32*)(dst + (size_t)(c0 + oR)*dcols + r0 + oC) = pk;
  }
}

// ================= Launch 1: mega-prep (all independent preprocessing + rank) =================
#define P_R1 2048
#define P_R2 2112
#define P_R3 2368
#define P_R4 2400
#define P_R5 2409
#define P_R6 2411
#define P_R7 2415
#define P_NB 2423
__global__ __launch_bounds__(256) void prep_kernel(
    const float* __restrict__ features, const float* __restrict__ W_feat,
    const float* __restrict__ Wq, const float* __restrict__ Wk,
    const float* __restrict__ Wv, const float* __restrict__ Wo,
    const float* __restrict__ W_p1, const float* __restrict__ b_p1,
    const float* __restrict__ W_p2, const float* __restrict__ b_p2,
    const float* __restrict__ b_feat, const float* __restrict__ bq,
    const float* __restrict__ bk, const float* __restrict__ bv,
    const float* __restrict__ coords,
    u16* __restrict__ featA, u16* __restrict__ W_feat_bf,
    u16* __restrict__ WqkvT, u16* __restrict__ WoT, u16* __restrict__ WcatT,
    u16* __restrict__ peD, float* __restrict__ bfq, float* __restrict__ biaskv,
    int* __restrict__ order, int* __restrict__ counts, int* __restrict__ cellstart)
{
  __shared__ __align__(16) char smem[34048];
  int bid = blockIdx.x, t = threadIdx.x;
  if (bid < P_R1){
    int i = bid*256 + t;
    float r[8]; load8(features + (size_t)i*8, r);
    *(uint4*)(featA + (size_t)i*8) = pack8(r);
  } else if (bid < P_R2){
    int i = (bid - P_R1)*256 + t;
    float r[8]; load8(W_feat + (size_t)i*8, r);
    *(uint4*)(W_feat_bf + (size_t)i*8) = pack8(r);
  } else if (bid < P_R3){
    int rel = bid - P_R2;
    int mat = rel >> 6, tile = rel & 63;
    int r0 = (tile >> 3)*64, c0 = (tile & 7)*64;
    const float* src = mat==0 ? Wq : (mat==1 ? Wk : (mat==2 ? Wv : Wo));
    u16* dst = mat==0 ? WqkvT : (mat==1 ? WqkvT + (size_t)512*DD
                     : (mat==2 ? WqkvT + (size_t)1024*DD : WoT));
    transpose64(src, DD, dst, DD, r0, c0, smem, t);
  } else if (bid < P_R4){
    int rel = bid - P_R3;                 // W_feat [256][512] -> WcatT [512][256]
    int r0 = (rel >> 3)*64, c0 = (rel & 7)*64;
    transpose64(W_feat, DD, WcatT, INDIM, r0, c0, smem, t);
  } else if (bid < P_R5){
    int kk = bid - P_R4;                  // pos-enc MLP -> peD
    float dx = (float)(kk/3 - 1), dy = (float)(kk%3 - 1);
    float* h = (float*)smem;
    float hv = dx*W_p1[t] + dy*W_p1[256 + t] + b_p1[t];
    h[t] = hv > 0.f ? hv : 0.f;
    __syncthreads();
    float acc0 = b_p2[t], acc1 = b_p2[t + 256];
    for (int c = 0; c < 256; c++){
      float hc = h[c];
      acc0 += hc * W_p2[(size_t)c*DD + t];
      acc1 += hc * W_p2[(size_t)c*DD + t + 256];
    }
    peD[(size_t)kk*DD + t]       = f2bf(acc0);
    peD[(size_t)kk*DD + t + 256] = f2bf(acc1);
  } else if (bid < P_R6){
    int i = (bid - P_R5)*256 + t;         // bfq = b_feat@Wq + bq
    float* bfs = (float*)smem;
    bfs[t] = b_feat[t]; bfs[t + 256] = b_feat[t + 256];
    __syncthreads();
    float acc = 0.f;
    for (int k = 0; k < DD; k++) acc += bfs[k] * Wq[(size_t)k*DD + i];
    bfq[i] = acc + bq[i];
  } else if (bid < P_R7){
    int n = (bid - P_R6)*256 + t;         // biaskv = b_feat@[Wk|Wv] + [bk|bv]
    float* bfs = (float*)smem;
    bfs[t] = b_feat[t]; bfs[t + 256] = b_feat[t + 256];
    __syncthreads();
    const float* W = (n < 512) ? Wk : Wv;
    int c = n & 511;
    float acc = 0.f;
    for (int k = 0; k < DD; k++) acc += bfs[k] * W[(size_t)k*DD + c];
    biaskv[n] = acc + ((n < 512) ? bk[c] : bv[c]);
  } else {
    int b = bid - P_R7;                   // rank: cell-id + stable counting sort
    u16 (*hist)[65] = (u16(*)[65])smem;
    int* tot  = (int*)(smem + 33280);
    int* base = (int*)(smem + 33536);
    #pragma unroll
    for (int i = 0; i < 65; i++) hist[t][i] = 0;
    int myc[8];
    float cxy[16];
    load8(coords + (size_t)(b*NPT + t*8)*2,     cxy);
    load8(coords + (size_t)(b*NPT + t*8)*2 + 8, cxy + 8);
    #pragma unroll
    for (int i = 0; i < 8; i++){
      int gx = (int)(cxy[2*i]   * (1.0f/32.0f)); gx = gx < 0 ? 0 : (gx > 7 ? 7 : gx);
      int gy = (int)(cxy[2*i+1] * (1.0f/32.0f)); gy = gy < 0 ? 0 : (gy > 7 ? 7 : gy);
      myc[i] = gx*8 + gy;
      hist[t][myc[i]]++;
    }
    __syncthreads();
    if (t < GG){
      int acc = 0;
      for (int tt = 0; tt < 256; tt++){ int v = hist[tt][t]; hist[tt][t] = (u16)acc; acc += v; }
      tot[t] = acc;
    }
    __syncthreads();
    if (t == 0){
      int acc = 0;
      for (int g = 0; g < GG; g++){ base[g] = acc; acc += tot[g]; }
    }
    __syncthreads();
    if (t < GG){
      counts[b*GG + t] = tot[t];
      cellstart[b*GG + t] = base[t];
    }
    #pragma unroll
    for (int i = 0; i < 8; i++){
      int g = myc[i];
      int local = 0;
      #pragma unroll
      for (int j = 0; j < 8; j++) local += (j < i && myc[j] == g) ? 1 : 0;
      order[b*NPT + base[g] + (int)hist[t][g] + local] = t*8 + i;
    }
  }
}

// ======== 2-phase pipelined GEMM core (shared SMEM buffer) ========
// SMEMB: >= 34816 bytes. lA dbuf [2][4096] u16, lB dbuf [2][4096] u16.
// Leaves acc/m0/n0/lane/lr/lrow/wn/wm/tid in scope. NWGv % 8 == 0.
#define BM 128
#define BN 128
#define GEMM_PIPE(SMEMB, Aptr, Btptr, Kv, GXv, NWGv, UIDX)                         \
  u16* lA_ = (u16*)(SMEMB);                                                        \
  u16* lB_ = (u16*)((char*)(SMEMB) + 16384);                                       \
  int orig_ = (UIDX);                                                              \
  int swz_ = (orig_ & 7)*((NWGv) >> 3) + (orig_ >> 3);                             \
  int m0 = (swz_ / (GXv)) * BM, n0 = (swz_ % (GXv)) * BN;                          \
  int lane = tid & 63;                                                             \
  int wv = tid >> 6;                                                               \
  int wm = (wv >> 1) * 64, wn = (wv & 1) * 64;                                     \
  int lr = lane & 15;                                                              \
  int kg = (lane >> 4) << 3;                                                       \
  f32x4 acc[4][4] = {};                                                            \
  {                                                                                \
    int srow = lane >> 2;                                                          \
    int scol = (lane & 3) << 3;                                                    \
    const u16* gA0 = (Aptr)  + (size_t)(m0 + wv*32 + srow)*(Kv) + scol;            \
    const u16* gB0 = (Btptr) + (size_t)(n0 + wv*32 + srow)*(Kv) + scol;            \
    int lofs = (wv*32)*32;                                                         \
    int steps = (Kv) >> 5;                                                         \
    gload16(gA0,                   lA_ + lofs);                                    \
    gload16(gA0 + (size_t)16*(Kv), lA_ + lofs + 512);                              \
    gload16(gB0,                   lB_ + lofs);                                    \
    gload16(gB0 + (size_t)16*(Kv), lB_ + lofs + 512);                              \
    __syncthreads();                                                               \
    for (int s = 0; s < steps; s++){                                               \
      int cur = s & 1;                                                             \
      u16* lAc = lA_ + cur*4096;                                                   \
      u16* lBc = lB_ + cur*4096;                                                   \
      if (s + 1 < steps){                                                          \
        int kt = (s + 1) << 5;                                                     \
        u16* lAn = lA_ + (cur^1)*4096;                                             \
        u16* lBn = lB_ + (cur^1)*4096;                                             \
        gload16(gA0 + kt,                   lAn + lofs);                           \
        gload16(gA0 + kt + (size_t)16*(Kv), lAn + lofs + 512);                     \
        gload16(gB0 + kt,                   lBn + lofs);                           \
        gload16(gB0 + kt + (size_t)16*(Kv), lBn + lofs + 512);                     \
      }                                                                            \
      bf16x8 af[4], bfv[4];                                                        \
      _Pragma("unroll")                                                            \
      for (int i = 0; i < 4; i++) af[i]  = *(const bf16x8*)&lAc[(wm + i*16 + lr)*32 + kg]; \
      _Pragma("unroll")                                                            \
      for (int j = 0; j < 4; j++) bfv[j] = *(const bf16x8*)&lBc[(wn + j*16 + lr)*32 + kg]; \
      _Pragma("unroll")                                                            \
      for (int i = 0; i < 4; i++)                                                  \
        _Pragma("unroll")                                                          \
        for (int j = 0; j < 4; j++)                                                \
          acc[i][j] = __builtin_amdgcn_mfma_f32_16x16x32_bf16(af[i], bfv[j], acc[i][j], 0, 0, 0); \
      __syncthreads();                                                             \
    }                                                                              \
  }                                                                                \
  int lrow = (lane >> 4) << 2;

// Coalesced bf16 epilogue: acc -> LDS [128][136] (2-way banks) -> 256B-contiguous stores.
#define EPI_BF16(SMEMB, DST, LDN, BIAS)                                            \
  {                                                                                \
    u16* Cs = (u16*)(SMEMB);                                                       \
    _Pragma("unroll")                                                              \
    for (int j = 0; j < 4; j++){                                                   \
      int col = wn + j*16 + lr;                                                    \
      float bcol = (BIAS)[n0 + col];                                               \
      _Pragma("unroll")                                                            \
      for (int i = 0; i < 4; i++){                                                 \
        int r0 = wm + i*16 + lrow;                                                 \
        _Pragma("unroll")                                                          \
        for (int r = 0; r < 4; r++)                                                \
          Cs[(r0 + r)*136 + col] = f2bf(acc[i][j][r] + bcol);                      \
      }                                                                            \
    }                                                                              \
    __syncthreads();                                                               \
    _Pragma("unroll")                                                              \
    for (int k = 0; k < 8; k++){                                                   \
      int idx = k*256 + tid;                                                       \
      int row = idx >> 4, c8 = (idx & 15) << 3;                                    \
      *(uint4*)&(DST)[(size_t)(m0 + row)*(LDN) + n0 + c8] = *(uint4*)&Cs[row*136 + c8]; \
    }                                                                              \
  }

// ========== Launch 2: smallgemm (24) + peKV (36) + meanF gather (512) + feat GEMM (512) ==========
__global__ __launch_bounds__(256) void mid_kernel(
    const u16* __restrict__ WqkvT, const u16* __restrict__ W_feat_bf,
    const u16* __restrict__ peD, u16* __restrict__ Xout, float* __restrict__ meanKV,
    const u16* __restrict__ featA, const int* __restrict__ order,
    const int* __restrict__ counts, const int* __restrict__ cellstart,
    u16* __restrict__ meanF, const u16* __restrict__ WcatT,
    const float* __restrict__ b_feat, u16* __restrict__ feat_bf)
{
  __shared__ __align__(16) char SMEM[34816];
  int tid = threadIdx.x;
  if (blockIdx.x < 24){
    // Xout[1536][256] = [Wq;Wk;Wv]^T @ W_feat^T  (bf16)
    GEMM_PIPE(SMEM, WqkvT, W_feat_bf, 512, 2, 24, (int)blockIdx.x)
    #pragma unroll
    for (int j = 0; j < 4; j++){
      int col = n0 + wn + j*16 + lr;
      #pragma unroll
      for (int i = 0; i < 4; i++){
        int row0 = m0 + wm + i*16 + lrow;
        #pragma unroll
        for (int r = 0; r < 4; r++)
          Xout[(size_t)(row0 + r)*INDIM + col] = f2bf(acc[i][j][r]);
      }
    }
  } else if (blockIdx.x < 60){
    float* pesh = (float*)SMEM;
    int bid2 = blockIdx.x - 24;
    int kk = bid2 >> 2, seg = bid2 & 3;
    int n = seg*256 + tid;
    pesh[tid]       = bf2f(peD[(size_t)kk*DD + tid]);
    pesh[tid + 256] = bf2f(peD[(size_t)kk*DD + tid + 256]);
    __syncthreads();
    const u16* wrow = WqkvT + (size_t)(512 + n)*DD;
    float acc = 0.f;
    for (int d8 = 0; d8 < 64; d8++){
      float w8[8]; load8bf(wrow + d8*8, w8);
      #pragma unroll
      for (int j = 0; j < 8; j++) acc += pesh[d8*8 + j]*w8[j];
    }
    meanKV[(size_t)(512 + kk)*1024 + n] = acc;
  } else if (blockIdx.x < 572){
    float (*part)[2] = (float(*)[2])SMEM;
    int bg = blockIdx.x - 60;             // 0..511
    int b = bg >> 6;
    int p = tid & 127, half = tid >> 7;
    int cnt = counts[bg], start = cellstart[bg];
    const int* ord = order + b*NPT + start;
    float a0 = 0.f, a1 = 0.f;
    for (int n = half; n < cnt; n += 2){
      u32 v = *(const u32*)(featA + (((size_t)(b*NPT + ord[n])) << 8) + p*2);
      a0 += bf2f((u16)v); a1 += bf2f((u16)(v >> 16));
    }
    if (half){ part[p][0] = a0; part[p][1] = a1; }
    __syncthreads();
    if (!half){
      a0 += part[p][0]; a1 += part[p][1];
      float inv = 1.f / (float)(cnt > 0 ? cnt : 1);
      *(u32*)(meanF + (size_t)bg*INDIM + p*2) =
          (u32)f2bf(a0*inv) | ((u32)f2bf(a1*inv) << 16);
    }
  } else {
    // feat = featA @ W_feat^T + b_feat  (M=16384, N=512, K=256)
    GEMM_PIPE(SMEM, featA, WcatT, 256, 4, 512, (int)blockIdx.x - 572)
    EPI_BF16(SMEM, feat_bf, DD, b_feat)
  }
}

// ========== Launch 3: q GEMM (512) + meanKV GEMM (32) = 544 blocks ==========
__global__ __launch_bounds__(256) void qmean_kernel(
    const u16* __restrict__ featA, const u16* __restrict__ WfqT,
    const u16* __restrict__ meanF, const u16* __restrict__ WfkvT,
    const float* __restrict__ bfq, const float* __restrict__ biaskv,
    u16* __restrict__ q_bf, float* __restrict__ meanKV)
{
  __shared__ __align__(16) char SMEM[34816];
  int tid = threadIdx.x;
  if (blockIdx.x < 512){
    // q = featA @ Wfq + bfq  (M=16384, N=512, K=256)
    GEMM_PIPE(SMEM, featA, WfqT, 256, 4, 512, (int)blockIdx.x)
    EPI_BF16(SMEM, q_bf, DD, bfq)
  } else {
    // meanKV rows 0..511 = meanF @ WfkvT^T + biaskv  (M=512, N=1024, K=256)
    GEMM_PIPE(SMEM, meanF, WfkvT, 256, 8, 32, (int)blockIdx.x - 512)
    #pragma unroll
    for (int j = 0; j < 4; j++){
      int col = n0 + wn + j*16 + lr;
      float bcol = biaskv[col];
      #pragma unroll
      for (int i = 0; i < 4; i++){
        int row0 = m0 + wm + i*16 + lrow;
        #pragma unroll
        for (int r = 0; r < 4; r++)
          meanKV[(size_t)(row0 + r)*1024 + col] = acc[i][j][r] + bcol;
      }
    }
  }
}

// ---------------- Launch 4: cell-centric attention: 1 block (1024 thr) per (b,cell) ----------------
__global__ __launch_bounds__(1024) void attn_cells(
    const u16* __restrict__ q, const float* __restrict__ meanKV,
    const int* __restrict__ order, const int* __restrict__ counts,
    const int* __restrict__ cellstart, u16* __restrict__ agg)
{
  int bg = blockIdx.x;            // 0..511
  int b = bg >> 6, c = bg & 63;
  int gx = c >> 3, gy = c & 7;
  __shared__ __align__(16) u16 Kf[9][DD];
  __shared__ __align__(16) u16 Vf[9][DD];
  __shared__ int vrow[9];
  int t = threadIdx.x;
  if (t < 9){
    int dx = t/3 - 1, dy = t%3 - 1;
    int nx = gx + dx, ny = gy + dy;
    int inb = ((unsigned)nx < 8u) && ((unsigned)ny < 8u);
    int row = b*GG + (((nx&7) << 3) | (ny&7));
    vrow[t] = (inb && counts[row] > 0) ? row : -1;
  }
  __syncthreads();
  int d = 2*(t & 255);
  for (int kk = (t >> 8); kk < 9; kk += 4){
    int row = vrow[kk];
    if (row >= 0){
      float2 mk = *(const float2*)&meanKV[(size_t)row*1024 + d];
      float2 pk = *(const float2*)&meanKV[(size_t)(512+kk)*1024 + d];
      float2 mv = *(const float2*)&meanKV[(size_t)row*1024 + 512 + d];
      float2 pv = *(const float2*)&meanKV[(size_t)(512+kk)*1024 + 512 + d];
      *(u32*)&Kf[kk][d] = (u32)f2bf(mk.x+pk.x) | ((u32)f2bf(mk.y+pk.y) << 16);
      *(u32*)&Vf[kk][d] = (u32)f2bf(mv.x+pv.x) | ((u32)f2bf(mv.y+pv.y) << 16);
    }
  }
  __syncthreads();
  int cnt = counts[bg];
  int wv = t >> 6, lane = t & 63;     // wv: 0..15
  const int* ord = order + b*NPT + cellstart[bg];
  for (int i = wv; i < cnt; i += 16){
    size_t p = (size_t)b*NPT + ord[i];
    float qv[8];
    load8bf(q + p*DD + lane*8, qv);
    float s[9];
    #pragma unroll
    for (int kk = 0; kk < 9; kk++){
      float partial = 0.f;
      if (vrow[kk] >= 0){
        float kv[8]; load8bf(&Kf[kk][lane*8], kv);
        #pragma unroll
        for (int j = 0; j < 8; j++) partial += qv[j]*kv[j];
      }
      partial += __shfl_xor(partial, 1);
      partial += __shfl_xor(partial, 2);
      partial += __shfl_xor(partial, 4);
      partial += __shfl_xor(partial, 8);
      s[kk] = (vrow[kk] >= 0) ? partial * 0.08838834764831843f : -1e30f;
    }
    float mx = s[0];
    #pragma unroll
    for (int kk = 1; kk < 9; kk++) mx = fmaxf(mx, s[kk]);
    float w[9], sum = 0.f;
    #pragma unroll
    for (int kk = 0; kk < 9; kk++){
      w[kk] = (vrow[kk] >= 0) ? __expf(s[kk] - mx) : 0.f;
      sum += w[kk];
    }
    float inv = 1.f / sum;
    float a[8] = {0,0,0,0,0,0,0,0};
    #pragma unroll
    for (int kk = 0; kk < 9; kk++){
      if (vrow[kk] >= 0){
        float wk = w[kk] * inv;
        float vv[8]; load8bf(&Vf[kk][lane*8], vv);
        #pragma unroll
        for (int j = 0; j < 8; j++) a[j] += wk*vv[j];
      }
    }
    *(uint4*)&agg[p*DD + lane*8] = pack8(a);
  }
}

// ========== Launch 5: fused lin+LN. BM=32 x BN=512, 8 waves, 2-phase pipe, 2 blocks/CU ==========
// out = LN(feat + (agg @ Wo + bo)) * gamma + beta
__global__ __launch_bounds__(512) void linln_kernel(
    const u16* __restrict__ agg_bf, const u16* __restrict__ WoT,
    const float* __restrict__ bo, const u16* __restrict__ feat_bf,
    const float* __restrict__ gamma, const float* __restrict__ beta,
    float* __restrict__ out)
{
  __shared__ __align__(16) char SMEM[69632];   // lA dbuf 4KB | lB dbuf 64KB; epilogue reuses
  u16* lA = (u16*)SMEM;                        // [2][1024] u16
  u16* lB = (u16*)(SMEM + 4096);               // [2][16384] u16
  int tid = threadIdx.x;
  int lane = tid & 63;
  int wvv = tid >> 6;                          // 0..7
  int m0 = blockIdx.x * 32;
  int wn2 = wvv * 64;                          // each wave: rows 0..31, cols [wn2, wn2+64)
  int lr = lane & 15;
  int kg = (lane >> 4) << 3;
  int srow = lane >> 2;
  int scol = (lane & 3) << 3;
  f32x4 acc[2][4] = {};
  {
    const u16* gB0 = WoT + (size_t)(wvv*64 + srow)*DD + scol;   // wave stages B rows [wvv*64, +64)
    int lBoff = (wvv*64)*32;
    const u16* gA0 = agg_bf + (size_t)(m0 + (wvv&1)*16 + srow)*DD + scol;
    int lAoff = ((wvv&1)*16)*32;
    bool doA = (wvv < 2);
    // prologue: stage buf0
    #pragma unroll
    for (int c = 0; c < 4; c++)
      gload16(gB0 + (size_t)(c*16)*DD, lB + lBoff + c*16*32);
    if (doA) gload16(gA0, lA + lAoff);
    __syncthreads();
    for (int s = 0; s < 16; s++){
      int cur = s & 1;
      u16* lAc = lA + cur*1024;
      u16* lBc = lB + cur*16384;
      if (s + 1 < 16){
        int kt = (s + 1) << 5;
        u16* lAn = lA + (cur^1)*1024;
        u16* lBn = lB + (cur^1)*16384;
        #pragma unroll
        for (int c = 0; c < 4; c++)
          gload16(gB0 + kt + (size_t)(c*16)*DD, lBn + lBoff + c*16*32);
        if (doA) gload16(gA0 + kt, lAn + lAoff);
      }
      bf16x8 af[2], bfv[4];
      #pragma unroll
      for (int i = 0; i < 2; i++) af[i]  = *(const bf16x8*)&lAc[(i*16 + lr)*32 + kg];
      #pragma unroll
      for (int j = 0; j < 4; j++) bfv[j] = *(const bf16x8*)&lBc[(wn2 + j*16 + lr)*32 + kg];
      #pragma unroll
      for (int i = 0; i < 2; i++)
        #pragma unroll
        for (int j = 0; j < 4; j++)
          acc[i][j] = __builtin_amdgcn_mfma_f32_16x16x32_bf16(af[i], bfv[j], acc[i][j], 0, 0, 0);
      __syncthreads();
    }
  }
  // epilogue: acc + bo -> LDS bf16 [32][520] (same rounding as old lin_bf)
  int lrow = (lane >> 4) << 2;
  u16* Cs = (u16*)SMEM;                        // 32*520*2 = 33280 <= 69632
  #pragma unroll
  for (int j = 0; j < 4; j++){
    int col = wn2 + j*16 + lr;
    float bcol = bo[col];
    #pragma unroll
    for (int i = 0; i < 2; i++){
      int r0 = i*16 + lrow;
      #pragma unroll
      for (int r = 0; r < 4; r++)
        Cs[(r0 + r)*520 + col] = f2bf(acc[i][j][r] + bcol);
    }
  }
  __syncthreads();
  // LN: wave wvv handles rows [wvv*4, +4); identical reduction order to old ln_kernel
  float gv[8], bev[8];
  load8(gamma + lane*8, gv);
  load8(beta + lane*8, bev);
  #pragma unroll
  for (int rr = 0; rr < 4; rr++){
    int row = wvv*4 + rr;
    float lv[8], fv[8];
    load8bf_lds(&Cs[row*520 + lane*8], lv);
    load8bf(feat_bf + (size_t)(m0 + row)*DD + lane*8, fv);
    float e[8], s1 = 0.f, s2 = 0.f;
    #pragma unroll
    for (int j = 0; j < 8; j++){ e[j] = fv[j] + lv[j]; s1 += e[j]; s2 += e[j]*e[j]; }
    #pragma unroll
    for (int m = 1; m < 64; m <<= 1){ s1 += __shfl_xor(s1, m); s2 += __shfl_xor(s2, m); }
    float mu  = s1 * (1.f/512.f);
    float var = s2 * (1.f/512.f) - mu*mu;
    float istd = rsqrtf(var + 1e-5f);
    float o[8];
    #pragma unroll
    for (int j = 0; j < 8; j++) o[j] = (e[j] - mu)*istd*gv[j] + bev[j];
    store8(out + (size_t)(m0 + row)*DD + lane*8, o);
  }
}

extern "C" void kernel_launch(void* const* d_in, const int* in_sizes, int n_in,
                              void* d_out, int out_size, void* d_ws, size_t ws_size,
                              hipStream_t stream) {
  (void)in_sizes; (void)n_in; (void)out_size; (void)ws_size;
  const float* features = (const float*)d_in[0];
  const float* coords   = (const float*)d_in[1];
  const float* W_feat   = (const float*)d_in[2];
  const float* b_feat   = (const float*)d_in[3];
  const float* W_p1     = (const float*)d_in[4];
  const float* b_p1     = (const float*)d_in[5];
  const float* W_p2     = (const float*)d_in[6];
  const float* b_p2     = (const float*)d_in[7];
  const float* Wq = (const float*)d_in[8];  const float* bq = (const float*)d_in[9];
  const float* Wk = (const float*)d_in[10]; const float* bk = (const float*)d_in[11];
  const float* Wv = (const float*)d_in[12]; const float* bv = (const float*)d_in[13];
  const float* Wo = (const float*)d_in[14]; const float* bo = (const float*)d_in[15];
  const float* gamma = (const float*)d_in[16]; const float* beta = (const float*)d_in[17];
  float* out = (float*)d_out;

  char* ws = (char*)d_ws;
  size_t off = 0;
  auto alloc = [&](size_t bytes) -> void* {
    void* p = ws + off;
    off = (off + bytes + 255) & ~(size_t)255;
    return p;
  };
  u16*   featA     = (u16*)  alloc((size_t)NPTS*INDIM*2);   // 8.4 MB
  u16*   feat_bf   = (u16*)  alloc((size_t)NPTS*DD*2);      // 16.8 MB
  u16*   q_bf      = (u16*)  alloc((size_t)NPTS*DD*2);      // 16.8 MB
  u16*   agg_bf    = (u16*)  alloc((size_t)NPTS*DD*2);      // 16.8 MB
  u16*   W_feat_bf = (u16*)  alloc((size_t)INDIM*DD*2);     // [256][512]
  u16*   WqkvT     = (u16*)  alloc((size_t)1536*DD*2);      // [Wq^T;Wk^T;Wv^T]
  u16*   WoT       = (u16*)  alloc((size_t)DD*DD*2);
  u16*   WcatT     = (u16*)  alloc((size_t)512*INDIM*2);    // W_feat^T [512][256]
  u16*   Xout      = (u16*)  alloc((size_t)1536*INDIM*2);   // [WfqT(512); WfkvT(1024)][256]
  u16*   peD       = (u16*)  alloc((size_t)9*DD*2);
  u16*   meanF     = (u16*)  alloc((size_t)512*INDIM*2);
  float* meanKV    = (float*)alloc((size_t)640*1024*4);     // rows 0..511 mean-derived, 512..520 pe
  float* bfq       = (float*)alloc((size_t)DD*4);
  float* biaskv    = (float*)alloc((size_t)1024*4);
  int*   order     = (int*)  alloc((size_t)NPTS*4);
  int*   counts    = (int*)  alloc((size_t)NBATCH*GG*4);
  int*   cellstart = (int*)  alloc((size_t)NBATCH*GG*4);
  u16*   WfqT      = Xout;                                  // [512][256]
  u16*   WfkvT     = Xout + (size_t)512*INDIM;              // [1024][256]

  // 1. mega-prep (+rank)
  prep_kernel<<<P_NB, 256, 0, stream>>>(
      features, W_feat, Wq, Wk, Wv, Wo, W_p1, b_p1, W_p2, b_p2,
      b_feat, bq, bk, bv, coords,
      featA, W_feat_bf, WqkvT, WoT, WcatT, peD, bfq, biaskv,
      order, counts, cellstart);
  // 2. [WfqT;WfkvT] GEMM + peKV rows + meanF gather + feat GEMM
  mid_kernel<<<1084, 256, 0, stream>>>(
      WqkvT, W_feat_bf, peD, Xout, meanKV, featA, order, counts, cellstart,
      meanF, WcatT, b_feat, feat_bf);
  // 3. q GEMM + meanKV rows 0..511 GEMM
  qmean_kernel<<<544, 256, 0, stream>>>(
      featA, WfqT, meanF, WfkvT, bfq, biaskv, q_bf, meanKV);
  // 4. cell-centric attention -> agg
  attn_cells<<<NBATCH*GG, 1024, 0, stream>>>(q_bf, meanKV, order, counts, cellstart, agg_bf);
  // 5. fused lin GEMM + residual + layernorm (BM=32, 512 blocks, 2 blocks/CU)
  linln_kernel<<<NPTS/32, 512, 0, stream>>>(agg_bf, WoT, bo, feat_bf, gamma, beta, out);
}

// Round 13
// 103.725 us; speedup vs baseline: 1.0310x; 1.0310x over previous
//
#include <hip/hip_runtime.h>
#include <stdint.h>

typedef unsigned short u16;
typedef unsigned int u32;
typedef __bf16 bf16x8 __attribute__((ext_vector_type(8)));
typedef float f32x4 __attribute__((ext_vector_type(4)));

#define NBATCH 8
#define NPT    2048
#define NPTS   16384     // NBATCH*NPT
#define INDIM  256
#define DD     512
#define GG     64        // 8x8 grid cells

__device__ __forceinline__ u16 f2bf(float f){
  u32 u = __builtin_bit_cast(u32, f);
  u += 0x7fffu + ((u >> 16) & 1u);
  return (u16)(u >> 16);
}
__device__ __forceinline__ float bf2f(u16 h){
  u32 u = ((u32)h) << 16;
  return __builtin_bit_cast(float, u);
}
__device__ __forceinline__ void load8(const float* __restrict__ p, float* r){
  float4 a = *(const float4*)p;
  float4 b = *(const float4*)(p + 4);
  r[0]=a.x;r[1]=a.y;r[2]=a.z;r[3]=a.w;r[4]=b.x;r[5]=b.y;r[6]=b.z;r[7]=b.w;
}
__device__ __forceinline__ void load8bf(const u16* __restrict__ p, float* r){
  uint4 v = *(const uint4*)p;
  r[0]=bf2f((u16)v.x); r[1]=bf2f((u16)(v.x>>16));
  r[2]=bf2f((u16)v.y); r[3]=bf2f((u16)(v.y>>16));
  r[4]=bf2f((u16)v.z); r[5]=bf2f((u16)(v.z>>16));
  r[6]=bf2f((u16)v.w); r[7]=bf2f((u16)(v.w>>16));
}
__device__ __forceinline__ void load8bf_lds(const u16* p, float* r){
  uint4 v = *(const uint4*)p;
  r[0]=bf2f((u16)v.x); r[1]=bf2f((u16)(v.x>>16));
  r[2]=bf2f((u16)v.y); r[3]=bf2f((u16)(v.y>>16));
  r[4]=bf2f((u16)v.z); r[5]=bf2f((u16)(v.z>>16));
  r[6]=bf2f((u16)v.w); r[7]=bf2f((u16)(v.w>>16));
}
__device__ __forceinline__ void store8(float* __restrict__ p, const float* r){
  float4 a; a.x=r[0];a.y=r[1];a.z=r[2];a.w=r[3];
  float4 b; b.x=r[4];b.y=r[5];b.z=r[6];b.w=r[7];
  *(float4*)p = a; *(float4*)(p+4) = b;
}
__device__ __forceinline__ uint4 pack8(const float* a){
  uint4 pk;
  pk.x = (u32)f2bf(a[0]) | ((u32)f2bf(a[1]) << 16);
  pk.y = (u32)f2bf(a[2]) | ((u32)f2bf(a[3]) << 16);
  pk.z = (u32)f2bf(a[4]) | ((u32)f2bf(a[5]) << 16);
  pk.w = (u32)f2bf(a[6]) | ((u32)f2bf(a[7]) << 16);
  return pk;
}
typedef __attribute__((address_space(1))) unsigned as1u;
typedef __attribute__((address_space(3))) unsigned as3u;
__device__ __forceinline__ void gload16(const void* g, void* l){
  __builtin_amdgcn_global_load_lds((as1u*)(uintptr_t)g, (as3u*)(uintptr_t)l, 16, 0, 0);
}

// ---- 64x64 LDS-tiled transpose: src f32[*][scols] -> dst bf16[*][dcols] ----
__device__ __forceinline__ void transpose64(const float* __restrict__ src, int scols,
                                            u16* __restrict__ dst, int dcols,
                                            int r0, int c0, char* smem, int t){
  float (*sh)[65] = (float(*)[65])smem;
  #pragma unroll
  for (int i = 0; i < 16; i++){
    int idx = i*256 + t;
    int r = idx >> 6, c = idx & 63;
    sh[r][c] = src[(size_t)(r0 + r)*scols + c0 + c];
  }
  __syncthreads();
  #pragma unroll
  for (int i = 0; i < 8; i++){
    int idx = i*512 + t*2;
    int oR = idx >> 6, oC = idx & 63;
    u32 pk = (u32)f2bf(sh[oC][oR]) | ((u32)f2bf(sh[oC+1][oR]) << 16);
    *(u32*)(dst + (size_t)(c0 + oR)*dcols + r0 + oC) = pk;
  }
}

// ================= Launch 1: mega-prep (all independent preprocessing + rank) =================
#define P_R1 2048
#define P_R2 2112
#define P_R3 2368
#define P_R4 2400
#define P_R5 2409
#define P_R6 2411
#define P_R7 2415
#define P_NB 2423
__global__ __launch_bounds__(256) void prep_kernel(
    const float* __restrict__ features, const float* __restrict__ W_feat,
    const float* __restrict__ Wq, const float* __restrict__ Wk,
    const float* __restrict__ Wv, const float* __restrict__ Wo,
    const float* __restrict__ W_p1, const float* __restrict__ b_p1,
    const float* __restrict__ W_p2, const float* __restrict__ b_p2,
    const float* __restrict__ b_feat, const float* __restrict__ bq,
    const float* __restrict__ bk, const float* __restrict__ bv,
    const float* __restrict__ coords,
    u16* __restrict__ featA, u16* __restrict__ W_feat_bf,
    u16* __restrict__ WqkvT, u16* __restrict__ WoT, u16* __restrict__ WcatT,
    u16* __restrict__ peD, float* __restrict__ bfq, float* __restrict__ biaskv,
    int* __restrict__ order, int* __restrict__ counts, int* __restrict__ cellstart)
{
  __shared__ __align__(16) char smem[34048];
  int bid = blockIdx.x, t = threadIdx.x;
  if (bid < P_R1){
    int i = bid*256 + t;
    float r[8]; load8(features + (size_t)i*8, r);
    *(uint4*)(featA + (size_t)i*8) = pack8(r);
  } else if (bid < P_R2){
    int i = (bid - P_R1)*256 + t;
    float r[8]; load8(W_feat + (size_t)i*8, r);
    *(uint4*)(W_feat_bf + (size_t)i*8) = pack8(r);
  } else if (bid < P_R3){
    int rel = bid - P_R2;
    int mat = rel >> 6, tile = rel & 63;
    int r0 = (tile >> 3)*64, c0 = (tile & 7)*64;
    const float* src = mat==0 ? Wq : (mat==1 ? Wk : (mat==2 ? Wv : Wo));
    u16* dst = mat==0 ? WqkvT : (mat==1 ? WqkvT + (size_t)512*DD
                     : (mat==2 ? WqkvT + (size_t)1024*DD : WoT));
    transpose64(src, DD, dst, DD, r0, c0, smem, t);
  } else if (bid < P_R4){
    int rel = bid - P_R3;                 // W_feat [256][512] -> WcatT [512][256]
    int r0 = (rel >> 3)*64, c0 = (rel & 7)*64;
    transpose64(W_feat, DD, WcatT, INDIM, r0, c0, smem, t);
  } else if (bid < P_R5){
    int kk = bid - P_R4;                  // pos-enc MLP -> peD
    float dx = (float)(kk/3 - 1), dy = (float)(kk%3 - 1);
    float* h = (float*)smem;
    float hv = dx*W_p1[t] + dy*W_p1[256 + t] + b_p1[t];
    h[t] = hv > 0.f ? hv : 0.f;
    __syncthreads();
    float acc0 = b_p2[t], acc1 = b_p2[t + 256];
    for (int c = 0; c < 256; c++){
      float hc = h[c];
      acc0 += hc * W_p2[(size_t)c*DD + t];
      acc1 += hc * W_p2[(size_t)c*DD + t + 256];
    }
    peD[(size_t)kk*DD + t]       = f2bf(acc0);
    peD[(size_t)kk*DD + t + 256] = f2bf(acc1);
  } else if (bid < P_R6){
    int i = (bid - P_R5)*256 + t;         // bfq = b_feat@Wq + bq
    float* bfs = (float*)smem;
    bfs[t] = b_feat[t]; bfs[t + 256] = b_feat[t + 256];
    __syncthreads();
    float acc = 0.f;
    for (int k = 0; k < DD; k++) acc += bfs[k] * Wq[(size_t)k*DD + i];
    bfq[i] = acc + bq[i];
  } else if (bid < P_R7){
    int n = (bid - P_R6)*256 + t;         // biaskv = b_feat@[Wk|Wv] + [bk|bv]
    float* bfs = (float*)smem;
    bfs[t] = b_feat[t]; bfs[t + 256] = b_feat[t + 256];
    __syncthreads();
    const float* W = (n < 512) ? Wk : Wv;
    int c = n & 511;
    float acc = 0.f;
    for (int k = 0; k < DD; k++) acc += bfs[k] * W[(size_t)k*DD + c];
    biaskv[n] = acc + ((n < 512) ? bk[c] : bv[c]);
  } else {
    int b = bid - P_R7;                   // rank: cell-id + stable counting sort
    u16 (*hist)[65] = (u16(*)[65])smem;
    int* tot  = (int*)(smem + 33280);
    int* base = (int*)(smem + 33536);
    #pragma unroll
    for (int i = 0; i < 65; i++) hist[t][i] = 0;
    int myc[8];
    float cxy[16];
    load8(coords + (size_t)(b*NPT + t*8)*2,     cxy);
    load8(coords + (size_t)(b*NPT + t*8)*2 + 8, cxy + 8);
    #pragma unroll
    for (int i = 0; i < 8; i++){
      int gx = (int)(cxy[2*i]   * (1.0f/32.0f)); gx = gx < 0 ? 0 : (gx > 7 ? 7 : gx);
      int gy = (int)(cxy[2*i+1] * (1.0f/32.0f)); gy = gy < 0 ? 0 : (gy > 7 ? 7 : gy);
      myc[i] = gx*8 + gy;
      hist[t][myc[i]]++;
    }
    __syncthreads();
    if (t < GG){
      int acc = 0;
      for (int tt = 0; tt < 256; tt++){ int v = hist[tt][t]; hist[tt][t] = (u16)acc; acc += v; }
      tot[t] = acc;
    }
    __syncthreads();
    if (t == 0){
      int acc = 0;
      for (int g = 0; g < GG; g++){ base[g] = acc; acc += tot[g]; }
    }
    __syncthreads();
    if (t < GG){
      counts[b*GG + t] = tot[t];
      cellstart[b*GG + t] = base[t];
    }
    #pragma unroll
    for (int i = 0; i < 8; i++){
      int g = myc[i];
      int local = 0;
      #pragma unroll
      for (int j = 0; j < 8; j++) local += (j < i && myc[j] == g) ? 1 : 0;
      order[b*NPT + base[g] + (int)hist[t][g] + local] = t*8 + i;
    }
  }
}

// ======== 2-phase pipelined GEMM core (shared SMEM buffer) ========
// SMEMB: >= 34816 bytes. lA dbuf [2][4096] u16, lB dbuf [2][4096] u16.
// Leaves acc/m0/n0/lane/lr/lrow/wn/wm/tid in scope. NWGv % 8 == 0.
#define BM 128
#define BN 128
#define GEMM_PIPE(SMEMB, Aptr, Btptr, Kv, GXv, NWGv, UIDX)                         \
  u16* lA_ = (u16*)(SMEMB);                                                        \
  u16* lB_ = (u16*)((char*)(SMEMB) + 16384);                                       \
  int orig_ = (UIDX);                                                              \
  int swz_ = (orig_ & 7)*((NWGv) >> 3) + (orig_ >> 3);                             \
  int m0 = (swz_ / (GXv)) * BM, n0 = (swz_ % (GXv)) * BN;                          \
  int lane = tid & 63;                                                             \
  int wv = tid >> 6;                                                               \
  int wm = (wv >> 1) * 64, wn = (wv & 1) * 64;                                     \
  int lr = lane & 15;                                                              \
  int kg = (lane >> 4) << 3;                                                       \
  f32x4 acc[4][4] = {};                                                            \
  {                                                                                \
    int srow = lane >> 2;                                                          \
    int scol = (lane & 3) << 3;                                                    \
    const u16* gA0 = (Aptr)  + (size_t)(m0 + wv*32 + srow)*(Kv) + scol;            \
    const u16* gB0 = (Btptr) + (size_t)(n0 + wv*32 + srow)*(Kv) + scol;            \
    int lofs = (wv*32)*32;                                                         \
    int steps = (Kv) >> 5;                                                         \
    gload16(gA0,                   lA_ + lofs);                                    \
    gload16(gA0 + (size_t)16*(Kv), lA_ + lofs + 512);                              \
    gload16(gB0,                   lB_ + lofs);                                    \
    gload16(gB0 + (size_t)16*(Kv), lB_ + lofs + 512);                              \
    __syncthreads();                                                               \
    for (int s = 0; s < steps; s++){                                               \
      int cur = s & 1;                                                             \
      u16* lAc = lA_ + cur*4096;                                                   \
      u16* lBc = lB_ + cur*4096;                                                   \
      if (s + 1 < steps){                                                          \
        int kt = (s + 1) << 5;                                                     \
        u16* lAn = lA_ + (cur^1)*4096;                                             \
        u16* lBn = lB_ + (cur^1)*4096;                                             \
        gload16(gA0 + kt,                   lAn + lofs);                           \
        gload16(gA0 + kt + (size_t)16*(Kv), lAn + lofs + 512);                     \
        gload16(gB0 + kt,                   lBn + lofs);                           \
        gload16(gB0 + kt + (size_t)16*(Kv), lBn + lofs + 512);                     \
      }                                                                            \
      bf16x8 af[4], bfv[4];                                                        \
      _Pragma("unroll")                                                            \
      for (int i = 0; i < 4; i++) af[i]  = *(const bf16x8*)&lAc[(wm + i*16 + lr)*32 + kg]; \
      _Pragma("unroll")                                                            \
      for (int j = 0; j < 4; j++) bfv[j] = *(const bf16x8*)&lBc[(wn + j*16 + lr)*32 + kg]; \
      _Pragma("unroll")                                                            \
      for (int i = 0; i < 4; i++)                                                  \
        _Pragma("unroll")                                                          \
        for (int j = 0; j < 4; j++)                                                \
          acc[i][j] = __builtin_amdgcn_mfma_f32_16x16x32_bf16(af[i], bfv[j], acc[i][j], 0, 0, 0); \
      __syncthreads();                                                             \
    }                                                                              \
  }                                                                                \
  int lrow = (lane >> 4) << 2;

// Coalesced bf16 epilogue: acc -> LDS [128][136] (2-way banks) -> 256B-contiguous stores.
#define EPI_BF16(SMEMB, DST, LDN, BIAS)                                            \
  {                                                                                \
    u16* Cs = (u16*)(SMEMB);                                                       \
    _Pragma("unroll")                                                              \
    for (int j = 0; j < 4; j++){                                                   \
      int col = wn + j*16 + lr;                                                    \
      float bcol = (BIAS)[n0 + col];                                               \
      _Pragma("unroll")                                                            \
      for (int i = 0; i < 4; i++){                                                 \
        int r0 = wm + i*16 + lrow;                                                 \
        _Pragma("unroll")                                                          \
        for (int r = 0; r < 4; r++)                                                \
          Cs[(r0 + r)*136 + col] = f2bf(acc[i][j][r] + bcol);                      \
      }                                                                            \
    }                                                                              \
    __syncthreads();                                                               \
    _Pragma("unroll")                                                              \
    for (int k = 0; k < 8; k++){                                                   \
      int idx = k*256 + tid;                                                       \
      int row = idx >> 4, c8 = (idx & 15) << 3;                                    \
      *(uint4*)&(DST)[(size_t)(m0 + row)*(LDN) + n0 + c8] = *(uint4*)&Cs[row*136 + c8]; \
    }                                                                              \
  }

// ========== Launch 2: smallgemm (24) + peKV (36) + meanF gather (512) + feat GEMM (512) ==========
__global__ __launch_bounds__(256) void mid_kernel(
    const u16* __restrict__ WqkvT, const u16* __restrict__ W_feat_bf,
    const u16* __restrict__ peD, u16* __restrict__ Xout, float* __restrict__ meanKV,
    const u16* __restrict__ featA, const int* __restrict__ order,
    const int* __restrict__ counts, const int* __restrict__ cellstart,
    u16* __restrict__ meanF, const u16* __restrict__ WcatT,
    const float* __restrict__ b_feat, u16* __restrict__ feat_bf)
{
  __shared__ __align__(16) char SMEM[34816];
  int tid = threadIdx.x;
  if (blockIdx.x < 24){
    // Xout[1536][256] = [Wq;Wk;Wv]^T @ W_feat^T  (bf16)
    GEMM_PIPE(SMEM, WqkvT, W_feat_bf, 512, 2, 24, (int)blockIdx.x)
    #pragma unroll
    for (int j = 0; j < 4; j++){
      int col = n0 + wn + j*16 + lr;
      #pragma unroll
      for (int i = 0; i < 4; i++){
        int row0 = m0 + wm + i*16 + lrow;
        #pragma unroll
        for (int r = 0; r < 4; r++)
          Xout[(size_t)(row0 + r)*INDIM + col] = f2bf(acc[i][j][r]);
      }
    }
  } else if (blockIdx.x < 60){
    float* pesh = (float*)SMEM;
    int bid2 = blockIdx.x - 24;
    int kk = bid2 >> 2, seg = bid2 & 3;
    int n = seg*256 + tid;
    pesh[tid]       = bf2f(peD[(size_t)kk*DD + tid]);
    pesh[tid + 256] = bf2f(peD[(size_t)kk*DD + tid + 256]);
    __syncthreads();
    const u16* wrow = WqkvT + (size_t)(512 + n)*DD;
    float acc = 0.f;
    for (int d8 = 0; d8 < 64; d8++){
      float w8[8]; load8bf(wrow + d8*8, w8);
      #pragma unroll
      for (int j = 0; j < 8; j++) acc += pesh[d8*8 + j]*w8[j];
    }
    meanKV[(size_t)(512 + kk)*1024 + n] = acc;
  } else if (blockIdx.x < 572){
    float (*part)[2] = (float(*)[2])SMEM;
    int bg = blockIdx.x - 60;             // 0..511
    int b = bg >> 6;
    int p = tid & 127, half = tid >> 7;
    int cnt = counts[bg], start = cellstart[bg];
    const int* ord = order + b*NPT + start;
    float a0 = 0.f, a1 = 0.f;
    for (int n = half; n < cnt; n += 2){
      u32 v = *(const u32*)(featA + (((size_t)(b*NPT + ord[n])) << 8) + p*2);
      a0 += bf2f((u16)v); a1 += bf2f((u16)(v >> 16));
    }
    if (half){ part[p][0] = a0; part[p][1] = a1; }
    __syncthreads();
    if (!half){
      a0 += part[p][0]; a1 += part[p][1];
      float inv = 1.f / (float)(cnt > 0 ? cnt : 1);
      *(u32*)(meanF + (size_t)bg*INDIM + p*2) =
          (u32)f2bf(a0*inv) | ((u32)f2bf(a1*inv) << 16);
    }
  } else {
    // feat = featA @ W_feat^T + b_feat  (M=16384, N=512, K=256)
    GEMM_PIPE(SMEM, featA, WcatT, 256, 4, 512, (int)blockIdx.x - 572)
    EPI_BF16(SMEM, feat_bf, DD, b_feat)
  }
}

// ========== Launch 3: q GEMM (512) + meanKV GEMM (32) = 544 blocks ==========
__global__ __launch_bounds__(256) void qmean_kernel(
    const u16* __restrict__ featA, const u16* __restrict__ WfqT,
    const u16* __restrict__ meanF, const u16* __restrict__ WfkvT,
    const float* __restrict__ bfq, const float* __restrict__ biaskv,
    u16* __restrict__ q_bf, float* __restrict__ meanKV)
{
  __shared__ __align__(16) char SMEM[34816];
  int tid = threadIdx.x;
  if (blockIdx.x < 512){
    // q = featA @ Wfq + bfq  (M=16384, N=512, K=256)
    GEMM_PIPE(SMEM, featA, WfqT, 256, 4, 512, (int)blockIdx.x)
    EPI_BF16(SMEM, q_bf, DD, bfq)
  } else {
    // meanKV rows 0..511 = meanF @ WfkvT^T + biaskv  (M=512, N=1024, K=256)
    GEMM_PIPE(SMEM, meanF, WfkvT, 256, 8, 32, (int)blockIdx.x - 512)
    #pragma unroll
    for (int j = 0; j < 4; j++){
      int col = n0 + wn + j*16 + lr;
      float bcol = biaskv[col];
      #pragma unroll
      for (int i = 0; i < 4; i++){
        int row0 = m0 + wm + i*16 + lrow;
        #pragma unroll
        for (int r = 0; r < 4; r++)
          meanKV[(size_t)(row0 + r)*1024 + col] = acc[i][j][r] + bcol;
      }
    }
  }
}

// ---------------- Launch 4: cell-centric attention: 1 block (1024 thr) per (b,cell) ----------------
__global__ __launch_bounds__(1024) void attn_cells(
    const u16* __restrict__ q, const float* __restrict__ meanKV,
    const int* __restrict__ order, const int* __restrict__ counts,
    const int* __restrict__ cellstart, u16* __restrict__ agg)
{
  int bg = blockIdx.x;            // 0..511
  int b = bg >> 6, c = bg & 63;
  int gx = c >> 3, gy = c & 7;
  __shared__ __align__(16) u16 Kf[9][DD];
  __shared__ __align__(16) u16 Vf[9][DD];
  __shared__ int vrow[9];
  int t = threadIdx.x;
  if (t < 9){
    int dx = t/3 - 1, dy = t%3 - 1;
    int nx = gx + dx, ny = gy + dy;
    int inb = ((unsigned)nx < 8u) && ((unsigned)ny < 8u);
    int row = b*GG + (((nx&7) << 3) | (ny&7));
    vrow[t] = (inb && counts[row] > 0) ? row : -1;
  }
  __syncthreads();
  int d = 2*(t & 255);
  for (int kk = (t >> 8); kk < 9; kk += 4){
    int row = vrow[kk];
    if (row >= 0){
      float2 mk = *(const float2*)&meanKV[(size_t)row*1024 + d];
      float2 pk = *(const float2*)&meanKV[(size_t)(512+kk)*1024 + d];
      float2 mv = *(const float2*)&meanKV[(size_t)row*1024 + 512 + d];
      float2 pv = *(const float2*)&meanKV[(size_t)(512+kk)*1024 + 512 + d];
      *(u32*)&Kf[kk][d] = (u32)f2bf(mk.x+pk.x) | ((u32)f2bf(mk.y+pk.y) << 16);
      *(u32*)&Vf[kk][d] = (u32)f2bf(mv.x+pv.x) | ((u32)f2bf(mv.y+pv.y) << 16);
    }
  }
  __syncthreads();
  int cnt = counts[bg];
  int wv = t >> 6, lane = t & 63;     // wv: 0..15
  const int* ord = order + b*NPT + cellstart[bg];
  for (int i = wv; i < cnt; i += 16){
    size_t p = (size_t)b*NPT + ord[i];
    float qv[8];
    load8bf(q + p*DD + lane*8, qv);
    float s[9];
    #pragma unroll
    for (int kk = 0; kk < 9; kk++){
      float partial = 0.f;
      if (vrow[kk] >= 0){
        float kv[8]; load8bf(&Kf[kk][lane*8], kv);
        #pragma unroll
        for (int j = 0; j < 8; j++) partial += qv[j]*kv[j];
      }
      partial += __shfl_xor(partial, 1);
      partial += __shfl_xor(partial, 2);
      partial += __shfl_xor(partial, 4);
      partial += __shfl_xor(partial, 8);
      s[kk] = (vrow[kk] >= 0) ? partial * 0.08838834764831843f : -1e30f;
    }
    float mx = s[0];
    #pragma unroll
    for (int kk = 1; kk < 9; kk++) mx = fmaxf(mx, s[kk]);
    float w[9], sum = 0.f;
    #pragma unroll
    for (int kk = 0; kk < 9; kk++){
      w[kk] = (vrow[kk] >= 0) ? __expf(s[kk] - mx) : 0.f;
      sum += w[kk];
    }
    float inv = 1.f / sum;
    float a[8] = {0,0,0,0,0,0,0,0};
    #pragma unroll
    for (int kk = 0; kk < 9; kk++){
      if (vrow[kk] >= 0){
        float wk = w[kk] * inv;
        float vv[8]; load8bf(&Vf[kk][lane*8], vv);
        #pragma unroll
        for (int j = 0; j < 8; j++) a[j] += wk*vv[j];
      }
    }
    *(uint4*)&agg[p*DD + lane*8] = pack8(a);
  }
}

// ========== Launch 5: fused lin+LN. BM=64 x BN=512, 16 waves (1024 thr), 2-phase pipe ==========
// out = LN(feat + (agg @ Wo + bo)) * gamma + beta
__global__ __launch_bounds__(1024) void linln_kernel(
    const u16* __restrict__ agg_bf, const u16* __restrict__ WoT,
    const float* __restrict__ bo, const u16* __restrict__ feat_bf,
    const float* __restrict__ gamma, const float* __restrict__ beta,
    float* __restrict__ out)
{
  __shared__ __align__(16) char SMEM[73728];   // lA dbuf 8KB | lB dbuf 64KB; epilogue reuses
  u16* lA = (u16*)SMEM;                        // [2][2048] u16
  u16* lB = (u16*)(SMEM + 8192);               // [2][16384] u16
  int tid = threadIdx.x;
  int lane = tid & 63;
  int wvv = tid >> 6;                          // 0..15
  int m0 = blockIdx.x * 64;
  int wm3 = (wvv >> 2) * 16;                   // 0,16,32,48: wave tile 16 rows x 128 cols
  int wn3 = (wvv & 3) * 128;                   // 0..384
  int lr = lane & 15;
  int kg = (lane >> 4) << 3;
  int srow = lane >> 2;
  int scol = (lane & 3) << 3;
  f32x4 acc[8] = {};
  {
    const u16* gB0 = WoT + (size_t)(wvv*32 + srow)*DD + scol;   // wave stages B rows [wvv*32, +32)
    int lBoff = (wvv*32)*32;
    const u16* gA0 = agg_bf + (size_t)(m0 + wvv*16 + srow)*DD + scol;
    int lAoff = (wvv*16)*32;
    bool doA = (wvv < 4);                      // waves 0..3 stage A rows [wvv*16, +16)
    // prologue: stage buf0
    #pragma unroll
    for (int c = 0; c < 2; c++)
      gload16(gB0 + (size_t)(c*16)*DD, lB + lBoff + c*16*32);
    if (doA) gload16(gA0, lA + lAoff);
    __syncthreads();
    for (int s = 0; s < 16; s++){
      int cur = s & 1;
      u16* lAc = lA + cur*2048;
      u16* lBc = lB + cur*16384;
      if (s + 1 < 16){
        int kt = (s + 1) << 5;
        u16* lAn = lA + (cur^1)*2048;
        u16* lBn = lB + (cur^1)*16384;
        #pragma unroll
        for (int c = 0; c < 2; c++)
          gload16(gB0 + kt + (size_t)(c*16)*DD, lBn + lBoff + c*16*32);
        if (doA) gload16(gA0 + kt, lAn + lAoff);
      }
      bf16x8 af, bfv[8];
      af = *(const bf16x8*)&lAc[(wm3 + lr)*32 + kg];
      #pragma unroll
      for (int j = 0; j < 8; j++) bfv[j] = *(const bf16x8*)&lBc[(wn3 + j*16 + lr)*32 + kg];
      #pragma unroll
      for (int j = 0; j < 8; j++)
        acc[j] = __builtin_amdgcn_mfma_f32_16x16x32_bf16(af, bfv[j], acc[j], 0, 0, 0);
      __syncthreads();
    }
  }
  // epilogue: acc + bo -> LDS bf16 [64][520] (same rounding as old lin_bf)
  int lrow = (lane >> 4) << 2;
  u16* Cs = (u16*)SMEM;                        // 64*520*2 = 66560 <= 73728
  #pragma unroll
  for (int j = 0; j < 8; j++){
    int col = wn3 + j*16 + lr;
    float bcol = bo[col];
    int r0 = wm3 + lrow;
    #pragma unroll
    for (int r = 0; r < 4; r++)
      Cs[(r0 + r)*520 + col] = f2bf(acc[j][r] + bcol);
  }
  __syncthreads();
  // LN: wave wvv handles rows [wvv*4, +4); identical reduction order to old ln_kernel
  float gv[8], bev[8];
  load8(gamma + lane*8, gv);
  load8(beta + lane*8, bev);
  #pragma unroll
  for (int rr = 0; rr < 4; rr++){
    int row = wvv*4 + rr;
    float lv[8], fv[8];
    load8bf_lds(&Cs[row*520 + lane*8], lv);
    load8bf(feat_bf + (size_t)(m0 + row)*DD + lane*8, fv);
    float e[8], s1 = 0.f, s2 = 0.f;
    #pragma unroll
    for (int j = 0; j < 8; j++){ e[j] = fv[j] + lv[j]; s1 += e[j]; s2 += e[j]*e[j]; }
    #pragma unroll
    for (int m = 1; m < 64; m <<= 1){ s1 += __shfl_xor(s1, m); s2 += __shfl_xor(s2, m); }
    float mu  = s1 * (1.f/512.f);
    float var = s2 * (1.f/512.f) - mu*mu;
    float istd = rsqrtf(var + 1e-5f);
    float o[8];
    #pragma unroll
    for (int j = 0; j < 8; j++) o[j] = (e[j] - mu)*istd*gv[j] + bev[j];
    store8(out + (size_t)(m0 + row)*DD + lane*8, o);
  }
}

extern "C" void kernel_launch(void* const* d_in, const int* in_sizes, int n_in,
                              void* d_out, int out_size, void* d_ws, size_t ws_size,
                              hipStream_t stream) {
  (void)in_sizes; (void)n_in; (void)out_size; (void)ws_size;
  const float* features = (const float*)d_in[0];
  const float* coords   = (const float*)d_in[1];
  const float* W_feat   = (const float*)d_in[2];
  const float* b_feat   = (const float*)d_in[3];
  const float* W_p1     = (const float*)d_in[4];
  const float* b_p1     = (const float*)d_in[5];
  const float* W_p2     = (const float*)d_in[6];
  const float* b_p2     = (const float*)d_in[7];
  const float* Wq = (const float*)d_in[8];  const float* bq = (const float*)d_in[9];
  const float* Wk = (const float*)d_in[10]; const float* bk = (const float*)d_in[11];
  const float* Wv = (const float*)d_in[12]; const float* bv = (const float*)d_in[13];
  const float* Wo = (const float*)d_in[14]; const float* bo = (const float*)d_in[15];
  const float* gamma = (const float*)d_in[16]; const float* beta = (const float*)d_in[17];
  float* out = (float*)d_out;

  char* ws = (char*)d_ws;
  size_t off = 0;
  auto alloc = [&](size_t bytes) -> void* {
    void* p = ws + off;
    off = (off + bytes + 255) & ~(size_t)255;
    return p;
  };
  u16*   featA     = (u16*)  alloc((size_t)NPTS*INDIM*2);   // 8.4 MB
  u16*   feat_bf   = (u16*)  alloc((size_t)NPTS*DD*2);      // 16.8 MB
  u16*   q_bf      = (u16*)  alloc((size_t)NPTS*DD*2);      // 16.8 MB
  u16*   agg_bf    = (u16*)  alloc((size_t)NPTS*DD*2);      // 16.8 MB
  u16*   W_feat_bf = (u16*)  alloc((size_t)INDIM*DD*2);     // [256][512]
  u16*   WqkvT     = (u16*)  alloc((size_t)1536*DD*2);      // [Wq^T;Wk^T;Wv^T]
  u16*   WoT       = (u16*)  alloc((size_t)DD*DD*2);
  u16*   WcatT     = (u16*)  alloc((size_t)512*INDIM*2);    // W_feat^T [512][256]
  u16*   Xout      = (u16*)  alloc((size_t)1536*INDIM*2);   // [WfqT(512); WfkvT(1024)][256]
  u16*   peD       = (u16*)  alloc((size_t)9*DD*2);
  u16*   meanF     = (u16*)  alloc((size_t)512*INDIM*2);
  float* meanKV    = (float*)alloc((size_t)640*1024*4);     // rows 0..511 mean-derived, 512..520 pe
  float* bfq       = (float*)alloc((size_t)DD*4);
  float* biaskv    = (float*)alloc((size_t)1024*4);
  int*   order     = (int*)  alloc((size_t)NPTS*4);
  int*   counts    = (int*)  alloc((size_t)NBATCH*GG*4);
  int*   cellstart = (int*)  alloc((size_t)NBATCH*GG*4);
  u16*   WfqT      = Xout;                                  // [512][256]
  u16*   WfkvT     = Xout + (size_t)512*INDIM;              // [1024][256]

  // 1. mega-prep (+rank)
  prep_kernel<<<P_NB, 256, 0, stream>>>(
      features, W_feat, Wq, Wk, Wv, Wo, W_p1, b_p1, W_p2, b_p2,
      b_feat, bq, bk, bv, coords,
      featA, W_feat_bf, WqkvT, WoT, WcatT, peD, bfq, biaskv,
      order, counts, cellstart);
  // 2. [WfqT;WfkvT] GEMM + peKV rows + meanF gather + feat GEMM
  mid_kernel<<<1084, 256, 0, stream>>>(
      WqkvT, W_feat_bf, peD, Xout, meanKV, featA, order, counts, cellstart,
      meanF, WcatT, b_feat, feat_bf);
  // 3. q GEMM + meanKV rows 0..511 GEMM
  qmean_kernel<<<544, 256, 0, stream>>>(
      featA, WfqT, meanF, WfkvT, bfq, biaskv, q_bf, meanKV);
  // 4. cell-centric attention -> agg
  attn_cells<<<NBATCH*GG, 1024, 0, stream>>>(q_bf, meanKV, order, counts, cellstart, agg_bf);
  // 5. fused lin GEMM + residual + layernorm (BM=64, 16 waves/block)
  linln_kernel<<<NPTS/64, 1024, 0, stream>>>(agg_bf, WoT, bo, feat_bf, gamma, beta, out);
}

// Round 14
// 101.830 us; speedup vs baseline: 1.0502x; 1.0186x over previous
//
#include <hip/hip_runtime.h>
#include <stdint.h>

typedef unsigned short u16;
typedef unsigned int u32;
typedef __bf16 bf16x8 __attribute__((ext_vector_type(8)));
typedef float f32x4 __attribute__((ext_vector_type(4)));

#define NBATCH 8
#define NPT    2048
#define NPTS   16384     // NBATCH*NPT
#define INDIM  256
#define DD     512
#define GG     64        // 8x8 grid cells

__device__ __forceinline__ u16 f2bf(float f){
  u32 u = __builtin_bit_cast(u32, f);
  u += 0x7fffu + ((u >> 16) & 1u);
  return (u16)(u >> 16);
}
__device__ __forceinline__ float bf2f(u16 h){
  u32 u = ((u32)h) << 16;
  return __builtin_bit_cast(float, u);
}
__device__ __forceinline__ void load8(const float* __restrict__ p, float* r){
  float4 a = *(const float4*)p;
  float4 b = *(const float4*)(p + 4);
  r[0]=a.x;r[1]=a.y;r[2]=a.z;r[3]=a.w;r[4]=b.x;r[5]=b.y;r[6]=b.z;r[7]=b.w;
}
__device__ __forceinline__ void load8bf(const u16* __restrict__ p, float* r){
  uint4 v = *(const uint4*)p;
  r[0]=bf2f((u16)v.x); r[1]=bf2f((u16)(v.x>>16));
  r[2]=bf2f((u16)v.y); r[3]=bf2f((u16)(v.y>>16));
  r[4]=bf2f((u16)v.z); r[5]=bf2f((u16)(v.z>>16));
  r[6]=bf2f((u16)v.w); r[7]=bf2f((u16)(v.w>>16));
}
__device__ __forceinline__ void load8bf_lds(const u16* p, float* r){
  uint4 v = *(const uint4*)p;
  r[0]=bf2f((u16)v.x); r[1]=bf2f((u16)(v.x>>16));
  r[2]=bf2f((u16)v.y); r[3]=bf2f((u16)(v.y>>16));
  r[4]=bf2f((u16)v.z); r[5]=bf2f((u16)(v.z>>16));
  r[6]=bf2f((u16)v.w); r[7]=bf2f((u16)(v.w>>16));
}
__device__ __forceinline__ void store8(float* __restrict__ p, const float* r){
  float4 a; a.x=r[0];a.y=r[1];a.z=r[2];a.w=r[3];
  float4 b; b.x=r[4];b.y=r[5];b.z=r[6];b.w=r[7];
  *(float4*)p = a; *(float4*)(p+4) = b;
}
__device__ __forceinline__ uint4 pack8(const float* a){
  uint4 pk;
  pk.x = (u32)f2bf(a[0]) | ((u32)f2bf(a[1]) << 16);
  pk.y = (u32)f2bf(a[2]) | ((u32)f2bf(a[3]) << 16);
  pk.z = (u32)f2bf(a[4]) | ((u32)f2bf(a[5]) << 16);
  pk.w = (u32)f2bf(a[6]) | ((u32)f2bf(a[7]) << 16);
  return pk;
}
typedef __attribute__((address_space(1))) unsigned as1u;
typedef __attribute__((address_space(3))) unsigned as3u;
__device__ __forceinline__ void gload16(const void* g, void* l){
  __builtin_amdgcn_global_load_lds((as1u*)(uintptr_t)g, (as3u*)(uintptr_t)l, 16, 0, 0);
}

// ---- 64x64 LDS-tiled transpose: src f32[*][scols] -> dst bf16[*][dcols] ----
__device__ __forceinline__ void transpose64(const float* __restrict__ src, int scols,
                                            u16* __restrict__ dst, int dcols,
                                            int r0, int c0, char* smem, int t){
  float (*sh)[65] = (float(*)[65])smem;
  #pragma unroll
  for (int i = 0; i < 16; i++){
    int idx = i*256 + t;
    int r = idx >> 6, c = idx & 63;
    sh[r][c] = src[(size_t)(r0 + r)*scols + c0 + c];
  }
  __syncthreads();
  #pragma unroll
  for (int i = 0; i < 8; i++){
    int idx = i*512 + t*2;
    int oR = idx >> 6, oC = idx & 63;
    u32 pk = (u32)f2bf(sh[oC][oR]) | ((u32)f2bf(sh[oC+1][oR]) << 16);
    *(u32*)(dst + (size_t)(c0 + oR)*dcols + r0 + oC) = pk;
  }
}

// ================= Launch 1: mega-prep (all independent preprocessing + rank) =================
#define P_R1 2048
#define P_R2 2112
#define P_R3 2368
#define P_R4 2400
#define P_R5 2409
#define P_R6 2411
#define P_R7 2415
#define P_NB 2423
__global__ __launch_bounds__(256) void prep_kernel(
    const float* __restrict__ features, const float* __restrict__ W_feat,
    const float* __restrict__ Wq, const float* __restrict__ Wk,
    const float* __restrict__ Wv, const float* __restrict__ Wo,
    const float* __restrict__ W_p1, const float* __restrict__ b_p1,
    const float* __restrict__ W_p2, const float* __restrict__ b_p2,
    const float* __restrict__ b_feat, const float* __restrict__ bq,
    const float* __restrict__ bk, const float* __restrict__ bv,
    const float* __restrict__ coords,
    u16* __restrict__ featA, u16* __restrict__ W_feat_bf,
    u16* __restrict__ WqkvT, u16* __restrict__ WoT, u16* __restrict__ WcatT,
    u16* __restrict__ peD, float* __restrict__ bfq, float* __restrict__ biaskv,
    int* __restrict__ order, int* __restrict__ counts, int* __restrict__ cellstart)
{
  __shared__ __align__(16) char smem[34048];
  int bid = blockIdx.x, t = threadIdx.x;
  if (bid < P_R1){
    int i = bid*256 + t;
    float r[8]; load8(features + (size_t)i*8, r);
    *(uint4*)(featA + (size_t)i*8) = pack8(r);
  } else if (bid < P_R2){
    int i = (bid - P_R1)*256 + t;
    float r[8]; load8(W_feat + (size_t)i*8, r);
    *(uint4*)(W_feat_bf + (size_t)i*8) = pack8(r);
  } else if (bid < P_R3){
    int rel = bid - P_R2;
    int mat = rel >> 6, tile = rel & 63;
    int r0 = (tile >> 3)*64, c0 = (tile & 7)*64;
    const float* src = mat==0 ? Wq : (mat==1 ? Wk : (mat==2 ? Wv : Wo));
    u16* dst = mat==0 ? WqkvT : (mat==1 ? WqkvT + (size_t)512*DD
                     : (mat==2 ? WqkvT + (size_t)1024*DD : WoT));
    transpose64(src, DD, dst, DD, r0, c0, smem, t);
  } else if (bid < P_R4){
    int rel = bid - P_R3;                 // W_feat [256][512] -> WcatT [512][256]
    int r0 = (rel >> 3)*64, c0 = (rel & 7)*64;
    transpose64(W_feat, DD, WcatT, INDIM, r0, c0, smem, t);
  } else if (bid < P_R5){
    int kk = bid - P_R4;                  // pos-enc MLP -> peD
    float dx = (float)(kk/3 - 1), dy = (float)(kk%3 - 1);
    float* h = (float*)smem;
    float hv = dx*W_p1[t] + dy*W_p1[256 + t] + b_p1[t];
    h[t] = hv > 0.f ? hv : 0.f;
    __syncthreads();
    float acc0 = b_p2[t], acc1 = b_p2[t + 256];
    for (int c = 0; c < 256; c++){
      float hc = h[c];
      acc0 += hc * W_p2[(size_t)c*DD + t];
      acc1 += hc * W_p2[(size_t)c*DD + t + 256];
    }
    peD[(size_t)kk*DD + t]       = f2bf(acc0);
    peD[(size_t)kk*DD + t + 256] = f2bf(acc1);
  } else if (bid < P_R6){
    int i = (bid - P_R5)*256 + t;         // bfq = b_feat@Wq + bq
    float* bfs = (float*)smem;
    bfs[t] = b_feat[t]; bfs[t + 256] = b_feat[t + 256];
    __syncthreads();
    float acc = 0.f;
    for (int k = 0; k < DD; k++) acc += bfs[k] * Wq[(size_t)k*DD + i];
    bfq[i] = acc + bq[i];
  } else if (bid < P_R7){
    int n = (bid - P_R6)*256 + t;         // biaskv = b_feat@[Wk|Wv] + [bk|bv]
    float* bfs = (float*)smem;
    bfs[t] = b_feat[t]; bfs[t + 256] = b_feat[t + 256];
    __syncthreads();
    const float* W = (n < 512) ? Wk : Wv;
    int c = n & 511;
    float acc = 0.f;
    for (int k = 0; k < DD; k++) acc += bfs[k] * W[(size_t)k*DD + c];
    biaskv[n] = acc + ((n < 512) ? bk[c] : bv[c]);
  } else {
    int b = bid - P_R7;                   // rank: cell-id + stable counting sort
    u16 (*hist)[65] = (u16(*)[65])smem;
    int* tot  = (int*)(smem + 33280);
    int* base = (int*)(smem + 33536);
    #pragma unroll
    for (int i = 0; i < 65; i++) hist[t][i] = 0;
    int myc[8];
    float cxy[16];
    load8(coords + (size_t)(b*NPT + t*8)*2,     cxy);
    load8(coords + (size_t)(b*NPT + t*8)*2 + 8, cxy + 8);
    #pragma unroll
    for (int i = 0; i < 8; i++){
      int gx = (int)(cxy[2*i]   * (1.0f/32.0f)); gx = gx < 0 ? 0 : (gx > 7 ? 7 : gx);
      int gy = (int)(cxy[2*i+1] * (1.0f/32.0f)); gy = gy < 0 ? 0 : (gy > 7 ? 7 : gy);
      myc[i] = gx*8 + gy;
      hist[t][myc[i]]++;
    }
    __syncthreads();
    if (t < GG){
      int acc = 0;
      for (int tt = 0; tt < 256; tt++){ int v = hist[tt][t]; hist[tt][t] = (u16)acc; acc += v; }
      tot[t] = acc;
    }
    __syncthreads();
    if (t == 0){
      int acc = 0;
      for (int g = 0; g < GG; g++){ base[g] = acc; acc += tot[g]; }
    }
    __syncthreads();
    if (t < GG){
      counts[b*GG + t] = tot[t];
      cellstart[b*GG + t] = base[t];
    }
    #pragma unroll
    for (int i = 0; i < 8; i++){
      int g = myc[i];
      int local = 0;
      #pragma unroll
      for (int j = 0; j < 8; j++) local += (j < i && myc[j] == g) ? 1 : 0;
      order[b*NPT + base[g] + (int)hist[t][g] + local] = t*8 + i;
    }
  }
}

// ======== 2-phase pipelined GEMM core (shared SMEM buffer) ========
// SMEMB: >= 34816 bytes. lA dbuf [2][4096] u16, lB dbuf [2][4096] u16.
// Leaves acc/m0/n0/lane/lr/lrow/wn/wm/tid in scope. NWGv % 8 == 0.
#define BM 128
#define BN 128
#define GEMM_PIPE(SMEMB, Aptr, Btptr, Kv, GXv, NWGv, UIDX)                         \
  u16* lA_ = (u16*)(SMEMB);                                                        \
  u16* lB_ = (u16*)((char*)(SMEMB) + 16384);                                       \
  int orig_ = (UIDX);                                                              \
  int swz_ = (orig_ & 7)*((NWGv) >> 3) + (orig_ >> 3);                             \
  int m0 = (swz_ / (GXv)) * BM, n0 = (swz_ % (GXv)) * BN;                          \
  int lane = tid & 63;                                                             \
  int wv = tid >> 6;                                                               \
  int wm = (wv >> 1) * 64, wn = (wv & 1) * 64;                                     \
  int lr = lane & 15;                                                              \
  int kg = (lane >> 4) << 3;                                                       \
  f32x4 acc[4][4] = {};                                                            \
  {                                                                                \
    int srow = lane >> 2;                                                          \
    int scol = (lane & 3) << 3;                                                    \
    const u16* gA0 = (Aptr)  + (size_t)(m0 + wv*32 + srow)*(Kv) + scol;            \
    const u16* gB0 = (Btptr) + (size_t)(n0 + wv*32 + srow)*(Kv) + scol;            \
    int lofs = (wv*32)*32;                                                         \
    int steps = (Kv) >> 5;                                                         \
    gload16(gA0,                   lA_ + lofs);                                    \
    gload16(gA0 + (size_t)16*(Kv), lA_ + lofs + 512);                              \
    gload16(gB0,                   lB_ + lofs);                                    \
    gload16(gB0 + (size_t)16*(Kv), lB_ + lofs + 512);                              \
    __syncthreads();                                                               \
    for (int s = 0; s < steps; s++){                                               \
      int cur = s & 1;                                                             \
      u16* lAc = lA_ + cur*4096;                                                   \
      u16* lBc = lB_ + cur*4096;                                                   \
      if (s + 1 < steps){                                                          \
        int kt = (s + 1) << 5;                                                     \
        u16* lAn = lA_ + (cur^1)*4096;                                             \
        u16* lBn = lB_ + (cur^1)*4096;                                             \
        gload16(gA0 + kt,                   lAn + lofs);                           \
        gload16(gA0 + kt + (size_t)16*(Kv), lAn + lofs + 512);                     \
        gload16(gB0 + kt,                   lBn + lofs);                           \
        gload16(gB0 + kt + (size_t)16*(Kv), lBn + lofs + 512);                     \
      }                                                                            \
      bf16x8 af[4], bfv[4];                                                        \
      _Pragma("unroll")                                                            \
      for (int i = 0; i < 4; i++) af[i]  = *(const bf16x8*)&lAc[(wm + i*16 + lr)*32 + kg]; \
      _Pragma("unroll")                                                            \
      for (int j = 0; j < 4; j++) bfv[j] = *(const bf16x8*)&lBc[(wn + j*16 + lr)*32 + kg]; \
      _Pragma("unroll")                                                            \
      for (int i = 0; i < 4; i++)                                                  \
        _Pragma("unroll")                                                          \
        for (int j = 0; j < 4; j++)                                                \
          acc[i][j] = __builtin_amdgcn_mfma_f32_16x16x32_bf16(af[i], bfv[j], acc[i][j], 0, 0, 0); \
      __syncthreads();                                                             \
    }                                                                              \
  }                                                                                \
  int lrow = (lane >> 4) << 2;

// Coalesced bf16 epilogue: acc -> LDS [128][136] (2-way banks) -> 256B-contiguous stores.
#define EPI_BF16(SMEMB, DST, LDN, BIAS)                                            \
  {                                                                                \
    u16* Cs = (u16*)(SMEMB);                                                       \
    _Pragma("unroll")                                                              \
    for (int j = 0; j < 4; j++){                                                   \
      int col = wn + j*16 + lr;                                                    \
      float bcol = (BIAS)[n0 + col];                                               \
      _Pragma("unroll")                                                            \
      for (int i = 0; i < 4; i++){                                                 \
        int r0 = wm + i*16 + lrow;                                                 \
        _Pragma("unroll")                                                          \
        for (int r = 0; r < 4; r++)                                                \
          Cs[(r0 + r)*136 + col] = f2bf(acc[i][j][r] + bcol);                      \
      }                                                                            \
    }                                                                              \
    __syncthreads();                                                               \
    _Pragma("unroll")                                                              \
    for (int k = 0; k < 8; k++){                                                   \
      int idx = k*256 + tid;                                                       \
      int row = idx >> 4, c8 = (idx & 15) << 3;                                    \
      *(uint4*)&(DST)[(size_t)(m0 + row)*(LDN) + n0 + c8] = *(uint4*)&Cs[row*136 + c8]; \
    }                                                                              \
  }

// ========== Launch 2: smallgemm (24) + peKV (36) + meanF gather (512) + feat GEMM (512) ==========
__global__ __launch_bounds__(256) void mid_kernel(
    const u16* __restrict__ WqkvT, const u16* __restrict__ W_feat_bf,
    const u16* __restrict__ peD, u16* __restrict__ Xout, float* __restrict__ meanKV,
    const u16* __restrict__ featA, const int* __restrict__ order,
    const int* __restrict__ counts, const int* __restrict__ cellstart,
    u16* __restrict__ meanF, const u16* __restrict__ WcatT,
    const float* __restrict__ b_feat, u16* __restrict__ feat_bf)
{
  __shared__ __align__(16) char SMEM[34816];
  int tid = threadIdx.x;
  if (blockIdx.x < 24){
    // Xout[1536][256] = [Wq;Wk;Wv]^T @ W_feat^T  (bf16)
    GEMM_PIPE(SMEM, WqkvT, W_feat_bf, 512, 2, 24, (int)blockIdx.x)
    #pragma unroll
    for (int j = 0; j < 4; j++){
      int col = n0 + wn + j*16 + lr;
      #pragma unroll
      for (int i = 0; i < 4; i++){
        int row0 = m0 + wm + i*16 + lrow;
        #pragma unroll
        for (int r = 0; r < 4; r++)
          Xout[(size_t)(row0 + r)*INDIM + col] = f2bf(acc[i][j][r]);
      }
    }
  } else if (blockIdx.x < 60){
    float* pesh = (float*)SMEM;
    int bid2 = blockIdx.x - 24;
    int kk = bid2 >> 2, seg = bid2 & 3;
    int n = seg*256 + tid;
    pesh[tid]       = bf2f(peD[(size_t)kk*DD + tid]);
    pesh[tid + 256] = bf2f(peD[(size_t)kk*DD + tid + 256]);
    __syncthreads();
    const u16* wrow = WqkvT + (size_t)(512 + n)*DD;
    float acc = 0.f;
    for (int d8 = 0; d8 < 64; d8++){
      float w8[8]; load8bf(wrow + d8*8, w8);
      #pragma unroll
      for (int j = 0; j < 8; j++) acc += pesh[d8*8 + j]*w8[j];
    }
    meanKV[(size_t)(512 + kk)*1024 + n] = acc;
  } else if (blockIdx.x < 572){
    float (*part)[2] = (float(*)[2])SMEM;
    int bg = blockIdx.x - 60;             // 0..511
    int b = bg >> 6;
    int p = tid & 127, half = tid >> 7;
    int cnt = counts[bg], start = cellstart[bg];
    const int* ord = order + b*NPT + start;
    float a0 = 0.f, a1 = 0.f;
    for (int n = half; n < cnt; n += 2){
      u32 v = *(const u32*)(featA + (((size_t)(b*NPT + ord[n])) << 8) + p*2);
      a0 += bf2f((u16)v); a1 += bf2f((u16)(v >> 16));
    }
    if (half){ part[p][0] = a0; part[p][1] = a1; }
    __syncthreads();
    if (!half){
      a0 += part[p][0]; a1 += part[p][1];
      float inv = 1.f / (float)(cnt > 0 ? cnt : 1);
      *(u32*)(meanF + (size_t)bg*INDIM + p*2) =
          (u32)f2bf(a0*inv) | ((u32)f2bf(a1*inv) << 16);
    }
  } else {
    // feat = featA @ W_feat^T + b_feat  (M=16384, N=512, K=256)
    GEMM_PIPE(SMEM, featA, WcatT, 256, 4, 512, (int)blockIdx.x - 572)
    EPI_BF16(SMEM, feat_bf, DD, b_feat)
  }
}

// ========== Launch 3: q GEMM (512) + meanKV GEMM (32) = 544 blocks ==========
__global__ __launch_bounds__(256) void qmean_kernel(
    const u16* __restrict__ featA, const u16* __restrict__ WfqT,
    const u16* __restrict__ meanF, const u16* __restrict__ WfkvT,
    const float* __restrict__ bfq, const float* __restrict__ biaskv,
    u16* __restrict__ q_bf, float* __restrict__ meanKV)
{
  __shared__ __align__(16) char SMEM[34816];
  int tid = threadIdx.x;
  if (blockIdx.x < 512){
    // q = featA @ Wfq + bfq  (M=16384, N=512, K=256)
    GEMM_PIPE(SMEM, featA, WfqT, 256, 4, 512, (int)blockIdx.x)
    EPI_BF16(SMEM, q_bf, DD, bfq)
  } else {
    // meanKV rows 0..511 = meanF @ WfkvT^T + biaskv  (M=512, N=1024, K=256)
    GEMM_PIPE(SMEM, meanF, WfkvT, 256, 8, 32, (int)blockIdx.x - 512)
    #pragma unroll
    for (int j = 0; j < 4; j++){
      int col = n0 + wn + j*16 + lr;
      float bcol = biaskv[col];
      #pragma unroll
      for (int i = 0; i < 4; i++){
        int row0 = m0 + wm + i*16 + lrow;
        #pragma unroll
        for (int r = 0; r < 4; r++)
          meanKV[(size_t)(row0 + r)*1024 + col] = acc[i][j][r] + bcol;
      }
    }
  }
}

// ---------------- Launch 4: cell-centric attention: 1 block (1024 thr) per (b,cell) ----------------
__global__ __launch_bounds__(1024) void attn_cells(
    const u16* __restrict__ q, const float* __restrict__ meanKV,
    const int* __restrict__ order, const int* __restrict__ counts,
    const int* __restrict__ cellstart, u16* __restrict__ agg)
{
  int bg = blockIdx.x;            // 0..511
  int b = bg >> 6, c = bg & 63;
  int gx = c >> 3, gy = c & 7;
  __shared__ __align__(16) u16 Kf[9][DD];
  __shared__ __align__(16) u16 Vf[9][DD];
  __shared__ int vrow[9];
  int t = threadIdx.x;
  if (t < 9){
    int dx = t/3 - 1, dy = t%3 - 1;
    int nx = gx + dx, ny = gy + dy;
    int inb = ((unsigned)nx < 8u) && ((unsigned)ny < 8u);
    int row = b*GG + (((nx&7) << 3) | (ny&7));
    vrow[t] = (inb && counts[row] > 0) ? row : -1;
  }
  __syncthreads();
  int d = 2*(t & 255);
  for (int kk = (t >> 8); kk < 9; kk += 4){
    int row = vrow[kk];
    if (row >= 0){
      float2 mk = *(const float2*)&meanKV[(size_t)row*1024 + d];
      float2 pk = *(const float2*)&meanKV[(size_t)(512+kk)*1024 + d];
      float2 mv = *(const float2*)&meanKV[(size_t)row*1024 + 512 + d];
      float2 pv = *(const float2*)&meanKV[(size_t)(512+kk)*1024 + 512 + d];
      *(u32*)&Kf[kk][d] = (u32)f2bf(mk.x+pk.x) | ((u32)f2bf(mk.y+pk.y) << 16);
      *(u32*)&Vf[kk][d] = (u32)f2bf(mv.x+pv.x) | ((u32)f2bf(mv.y+pv.y) << 16);
    }
  }
  __syncthreads();
  int cnt = counts[bg];
  int wv = t >> 6, lane = t & 63;     // wv: 0..15
  const int* ord = order + b*NPT + cellstart[bg];
  for (int i = wv; i < cnt; i += 16){
    size_t p = (size_t)b*NPT + ord[i];
    float qv[8];
    load8bf(q + p*DD + lane*8, qv);
    float s[9];
    #pragma unroll
    for (int kk = 0; kk < 9; kk++){
      float partial = 0.f;
      if (vrow[kk] >= 0){
        float kv[8]; load8bf(&Kf[kk][lane*8], kv);
        #pragma unroll
        for (int j = 0; j < 8; j++) partial += qv[j]*kv[j];
      }
      partial += __shfl_xor(partial, 1);
      partial += __shfl_xor(partial, 2);
      partial += __shfl_xor(partial, 4);
      partial += __shfl_xor(partial, 8);
      s[kk] = (vrow[kk] >= 0) ? partial * 0.08838834764831843f : -1e30f;
    }
    float mx = s[0];
    #pragma unroll
    for (int kk = 1; kk < 9; kk++) mx = fmaxf(mx, s[kk]);
    float w[9], sum = 0.f;
    #pragma unroll
    for (int kk = 0; kk < 9; kk++){
      w[kk] = (vrow[kk] >= 0) ? __expf(s[kk] - mx) : 0.f;
      sum += w[kk];
    }
    float inv = 1.f / sum;
    float a[8] = {0,0,0,0,0,0,0,0};
    #pragma unroll
    for (int kk = 0; kk < 9; kk++){
      if (vrow[kk] >= 0){
        float wk = w[kk] * inv;
        float vv[8]; load8bf(&Vf[kk][lane*8], vv);
        #pragma unroll
        for (int j = 0; j < 8; j++) a[j] += wk*vv[j];
      }
    }
    *(uint4*)&agg[p*DD + lane*8] = pack8(a);
  }
}

// ========== Launch 5: fused lin+LN. BM=64 x BN=512 (full row), 8 waves, 2-phase pipe ==========
// out = LN(feat + (agg @ Wo + bo)) * gamma + beta
__global__ __launch_bounds__(512) void linln_kernel(
    const u16* __restrict__ agg_bf, const u16* __restrict__ WoT,
    const float* __restrict__ bo, const u16* __restrict__ feat_bf,
    const float* __restrict__ gamma, const float* __restrict__ beta,
    float* __restrict__ out)
{
  __shared__ __align__(16) char SMEM[73728];   // lA dbuf 8KB | lB dbuf 64KB; epilogue reuses
  u16* lA = (u16*)SMEM;                        // [2][2048] u16
  u16* lB = (u16*)(SMEM + 8192);               // [2][16384] u16
  int tid = threadIdx.x;
  int lane = tid & 63;
  int wvv = tid >> 6;                          // 0..7
  int m0 = blockIdx.x * 64;
  int wm2 = (wvv >> 2) * 32;                   // 0 / 32
  int wn2 = (wvv & 3) * 128;                   // 0..384
  int lr = lane & 15;
  int kg = (lane >> 4) << 3;
  int srow = lane >> 2;
  int scol = (lane & 3) << 3;
  f32x4 acc[2][8] = {};
  {
    const u16* gB0 = WoT + (size_t)(wvv*64 + srow)*DD + scol;   // wave stages B rows [wvv*64, +64)
    int lBoff = (wvv*64)*32;
    const u16* gA0 = agg_bf + (size_t)(m0 + (wvv&3)*16 + srow)*DD + scol;
    int lAoff = ((wvv&3)*16)*32;
    bool doA = (wvv < 4);
    // prologue: stage buf0
    #pragma unroll
    for (int c = 0; c < 4; c++)
      gload16(gB0 + (size_t)(c*16)*DD, lB + lBoff + c*16*32);
    if (doA) gload16(gA0, lA + lAoff);
    __syncthreads();
    for (int s = 0; s < 16; s++){
      int cur = s & 1;
      u16* lAc = lA + cur*2048;
      u16* lBc = lB + cur*16384;
      if (s + 1 < 16){
        int kt = (s + 1) << 5;
        u16* lAn = lA + (cur^1)*2048;
        u16* lBn = lB + (cur^1)*16384;
        #pragma unroll
        for (int c = 0; c < 4; c++)
          gload16(gB0 + kt + (size_t)(c*16)*DD, lBn + lBoff + c*16*32);
        if (doA) gload16(gA0 + kt, lAn + lAoff);
      }
      bf16x8 af[2], bfv[8];
      #pragma unroll
      for (int i = 0; i < 2; i++) af[i]  = *(const bf16x8*)&lAc[(wm2 + i*16 + lr)*32 + kg];
      #pragma unroll
      for (int j = 0; j < 8; j++) bfv[j] = *(const bf16x8*)&lBc[(wn2 + j*16 + lr)*32 + kg];
      #pragma unroll
      for (int i = 0; i < 2; i++)
        #pragma unroll
        for (int j = 0; j < 8; j++)
          acc[i][j] = __builtin_amdgcn_mfma_f32_16x16x32_bf16(af[i], bfv[j], acc[i][j], 0, 0, 0);
      __syncthreads();
    }
  }
  // epilogue: acc + bo -> LDS bf16 [64][520] (same rounding as old lin_bf)
  int lrow = (lane >> 4) << 2;
  u16* Cs = (u16*)SMEM;                        // 64*520*2 = 66560 <= 73728
  #pragma unroll
  for (int j = 0; j < 8; j++){
    int col = wn2 + j*16 + lr;
    float bcol = bo[col];
    #pragma unroll
    for (int i = 0; i < 2; i++){
      int r0 = wm2 + i*16 + lrow;
      #pragma unroll
      for (int r = 0; r < 4; r++)
        Cs[(r0 + r)*520 + col] = f2bf(acc[i][j][r] + bcol);
    }
  }
  __syncthreads();
  // LN: wave wvv handles rows [wvv*8, +8); identical reduction order to old ln_kernel
  float gv[8], bev[8];
  load8(gamma + lane*8, gv);
  load8(beta + lane*8, bev);
  for (int rr = 0; rr < 8; rr++){
    int row = wvv*8 + rr;
    float lv[8], fv[8];
    load8bf_lds(&Cs[row*520 + lane*8], lv);
    load8bf(feat_bf + (size_t)(m0 + row)*DD + lane*8, fv);
    float e[8], s1 = 0.f, s2 = 0.f;
    #pragma unroll
    for (int j = 0; j < 8; j++){ e[j] = fv[j] + lv[j]; s1 += e[j]; s2 += e[j]*e[j]; }
    #pragma unroll
    for (int m = 1; m < 64; m <<= 1){ s1 += __shfl_xor(s1, m); s2 += __shfl_xor(s2, m); }
    float mu  = s1 * (1.f/512.f);
    float var = s2 * (1.f/512.f) - mu*mu;
    float istd = rsqrtf(var + 1e-5f);
    float o[8];
    #pragma unroll
    for (int j = 0; j < 8; j++) o[j] = (e[j] - mu)*istd*gv[j] + bev[j];
    store8(out + (size_t)(m0 + row)*DD + lane*8, o);
  }
}

extern "C" void kernel_launch(void* const* d_in, const int* in_sizes, int n_in,
                              void* d_out, int out_size, void* d_ws, size_t ws_size,
                              hipStream_t stream) {
  (void)in_sizes; (void)n_in; (void)out_size; (void)ws_size;
  const float* features = (const float*)d_in[0];
  const float* coords   = (const float*)d_in[1];
  const float* W_feat   = (const float*)d_in[2];
  const float* b_feat   = (const float*)d_in[3];
  const float* W_p1     = (const float*)d_in[4];
  const float* b_p1     = (const float*)d_in[5];
  const float* W_p2     = (const float*)d_in[6];
  const float* b_p2     = (const float*)d_in[7];
  const float* Wq = (const float*)d_in[8];  const float* bq = (const float*)d_in[9];
  const float* Wk = (const float*)d_in[10]; const float* bk = (const float*)d_in[11];
  const float* Wv = (const float*)d_in[12]; const float* bv = (const float*)d_in[13];
  const float* Wo = (const float*)d_in[14]; const float* bo = (const float*)d_in[15];
  const float* gamma = (const float*)d_in[16]; const float* beta = (const float*)d_in[17];
  float* out = (float*)d_out;

  char* ws = (char*)d_ws;
  size_t off = 0;
  auto alloc = [&](size_t bytes) -> void* {
    void* p = ws + off;
    off = (off + bytes + 255) & ~(size_t)255;
    return p;
  };
  u16*   featA     = (u16*)  alloc((size_t)NPTS*INDIM*2);   // 8.4 MB
  u16*   feat_bf   = (u16*)  alloc((size_t)NPTS*DD*2);      // 16.8 MB
  u16*   q_bf      = (u16*)  alloc((size_t)NPTS*DD*2);      // 16.8 MB
  u16*   agg_bf    = (u16*)  alloc((size_t)NPTS*DD*2);      // 16.8 MB
  u16*   W_feat_bf = (u16*)  alloc((size_t)INDIM*DD*2);     // [256][512]
  u16*   WqkvT     = (u16*)  alloc((size_t)1536*DD*2);      // [Wq^T;Wk^T;Wv^T]
  u16*   WoT       = (u16*)  alloc((size_t)DD*DD*2);
  u16*   WcatT     = (u16*)  alloc((size_t)512*INDIM*2);    // W_feat^T [512][256]
  u16*   Xout      = (u16*)  alloc((size_t)1536*INDIM*2);   // [WfqT(512); WfkvT(1024)][256]
  u16*   peD       = (u16*)  alloc((size_t)9*DD*2);
  u16*   meanF     = (u16*)  alloc((size_t)512*INDIM*2);
  float* meanKV    = (float*)alloc((size_t)640*1024*4);     // rows 0..511 mean-derived, 512..520 pe
  float* bfq       = (float*)alloc((size_t)DD*4);
  float* biaskv    = (float*)alloc((size_t)1024*4);
  int*   order     = (int*)  alloc((size_t)NPTS*4);
  int*   counts    = (int*)  alloc((size_t)NBATCH*GG*4);
  int*   cellstart = (int*)  alloc((size_t)NBATCH*GG*4);
  u16*   WfqT      = Xout;                                  // [512][256]
  u16*   WfkvT     = Xout + (size_t)512*INDIM;              // [1024][256]

  // 1. mega-prep (+rank)
  prep_kernel<<<P_NB, 256, 0, stream>>>(
      features, W_feat, Wq, Wk, Wv, Wo, W_p1, b_p1, W_p2, b_p2,
      b_feat, bq, bk, bv, coords,
      featA, W_feat_bf, WqkvT, WoT, WcatT, peD, bfq, biaskv,
      order, counts, cellstart);
  // 2. [WfqT;WfkvT] GEMM + peKV rows + meanF gather + feat GEMM
  mid_kernel<<<1084, 256, 0, stream>>>(
      WqkvT, W_feat_bf, peD, Xout, meanKV, featA, order, counts, cellstart,
      meanF, WcatT, b_feat, feat_bf);
  // 3. q GEMM + meanKV rows 0..511 GEMM
  qmean_kernel<<<544, 256, 0, stream>>>(
      featA, WfqT, meanF, WfkvT, bfq, biaskv, q_bf, meanKV);
  // 4. cell-centric attention -> agg
  attn_cells<<<NBATCH*GG, 1024, 0, stream>>>(q_bf, meanKV, order, counts, cellstart, agg_bf);
  // 5. fused lin GEMM + residual + layernorm
  linln_kernel<<<NPTS/64, 512, 0, stream>>>(agg_bf, WoT, bo, feat_bf, gamma, beta, out);
}